// Round 14
// baseline (282.097 us; speedup 1.0000x reference)
//
#include <hip/hip_runtime.h>
#include <hip/hip_bf16.h>
#include <math.h>

// DeformableAttention2D — round 14: k3a occupancy-cliff fix. r13 showed VALU
// ops halved but time unchanged -> latency-bound at 4 waves/SIMD (VGPR=72 >
// 64 cliff, occupancy 28%). Force __launch_bounds__(256,8) (VGPR cap 64):
// acc regs halved (process c2-tiles in 2 passes), b0 constants to LDS.
// Sizes (fixed): B=4, N=256, DIM=256, HEADS=8, GROUPS=8, INNER=512, DH=64,
// cross-attn head dim 32, rgb 4x4 (16 tokens), CPB MLP 2->64->64->1.

#define DIMC 256
#define NQ 256
#define HEADS 8
#define GROUPS 8
#define INNER 512
#define DH 64
#define HDX 32
#define HWT 16

typedef __attribute__((ext_vector_type(8))) short short8v;
typedef __attribute__((ext_vector_type(8))) _Float16 half8v;
typedef __attribute__((ext_vector_type(4))) float f32x4;
typedef unsigned short ushort_t;

__device__ __forceinline__ float gelu_exact(float x) {
    return 0.5f * x * (1.f + erff(x * 0.70710678118654752f));
}
__device__ __forceinline__ short f2bf(float x) {
    union { float f; unsigned u; } c; c.f = x;
    unsigned r = c.u + 0x7fffu + ((c.u >> 16) & 1u);
    return (short)(r >> 16);
}
__device__ __forceinline__ float bf2f(unsigned hbits) {
    union { unsigned u; float f; } c; c.u = hbits << 16;
    return c.f;
}
// packed fp16 helpers (avoid __half2 API — hip_bf16.h shadows overloads;
// cvt_pkrtz returns __fp16 ext_vector(2) — bitcast via decltype union)
__device__ __forceinline__ unsigned pkrtz(float a, float b) {
    auto h = __builtin_amdgcn_cvt_pkrtz(a, b);
    union { decltype(h) h2; unsigned u; } c; c.h2 = h; return c.u;
}
__device__ __forceinline__ unsigned pk_fma_f16(unsigned a, unsigned b, unsigned c) {
    unsigned d;
    asm("v_pk_fma_f16 %0, %1, %2, %3" : "=v"(d) : "v"(a), "v"(b), "v"(c));
    return d;
}
__device__ __forceinline__ unsigned pk_max0_f16(unsigned a) {
    unsigned d;
    asm("v_pk_max_f16 %0, %1, %2" : "=v"(d) : "v"(a), "v"(0u));
    return d;
}
__device__ __forceinline__ float samp4(const float* __restrict__ img, int yi, int xi) {
    bool valid = (xi >= 0) && (xi < 4) && (yi >= 0) && (yi < 4);
    int idx = min(max(yi, 0), 3) * 4 + min(max(xi, 0), 3);
    return valid ? img[idx] : 0.f;
}

// ---------------- K0: weight transposes ----------------
__global__ __launch_bounds__(256) void k0_tr(
        const float* __restrict__ in_w, const float* __restrict__ mow,
        const float* __restrict__ out_w, const float* __restrict__ q_w,
        const float* __restrict__ k_w, const float* __restrict__ v_w,
        float* __restrict__ WqT, float* __restrict__ mowT,
        float* __restrict__ owT, float* __restrict__ qwT,
        float* __restrict__ kwT, float* __restrict__ vwT) {
    int idx = blockIdx.x * 256 + threadIdx.x;
    if (idx < 65536) {
        int d = idx >> 8, o = idx & 255;
        WqT[idx] = in_w[o * 256 + d];
    } else if (idx < 131072) {
        int k = idx - 65536; int d = k >> 8, o = k & 255;
        mowT[k] = mow[o * 256 + d];
    } else if (idx < 262144) {
        int k = idx - 131072; int c = k >> 8, o = k & 255;
        owT[k] = out_w[o * 512 + c];
    } else if (idx < 278528) {
        int k = idx - 262144; int ci = k >> 9, ch = k & 511;
        qwT[k] = q_w[ch * 32 + ci];
    } else if (idx < 294912) {
        int k = idx - 278528; int ci = k >> 9, ch = k & 511;
        kwT[k] = k_w[ch * 32 + ci];
    } else if (idx < 311296) {
        int k = idx - 294912; int ci = k >> 9, ch = k & 511;
        vwT[k] = v_w[ch * 32 + ci];
    }
}

// ---------------- K1: kx, vx  [b,16,256] ----------------
__global__ __launch_bounds__(256) void k1_kv(const float* __restrict__ rgb,
        const float* __restrict__ in_w, const float* __restrict__ in_b,
        float* __restrict__ kx, float* __restrict__ vx) {
    int b = blockIdx.x >> 4;
    int tt = blockIdx.x & 15;
    int c = threadIdx.x;
    __shared__ __align__(16) float kvin[DIMC];
    float ang = (float)tt * powf(10000.f, -(float)(c >> 1) * (1.f / 128.f));
    float sv = (c & 1) ? cosf(ang) : sinf(ang);
    kvin[c] = rgb[(b * DIMC + c) * HWT + tt] + sv;
    __syncthreads();
    const float4* x4 = (const float4*)kvin;
    const float4* wk4 = (const float4*)(in_w + (DIMC + c) * DIMC);
    const float4* wv4 = (const float4*)(in_w + (2 * DIMC + c) * DIMC);
    float ak0 = in_b[DIMC + c], ak1 = 0.f, av0 = in_b[2 * DIMC + c], av1 = 0.f;
    #pragma unroll 4
    for (int d4 = 0; d4 < 64; ++d4) {
        float4 x = x4[d4], wk = wk4[d4], wv = wv4[d4];
        ak0 = fmaf(wk.x, x.x, ak0); ak1 = fmaf(wk.y, x.y, ak1);
        ak0 = fmaf(wk.z, x.z, ak0); ak1 = fmaf(wk.w, x.w, ak1);
        av0 = fmaf(wv.x, x.x, av0); av1 = fmaf(wv.y, x.y, av1);
        av0 = fmaf(wv.z, x.z, av0); av1 = fmaf(wv.w, x.w, av1);
    }
    kx[(b * HWT + tt) * DIMC + c] = ak0 + ak1;
    vx[(b * HWT + tt) * DIMC + c] = av0 + av1;
}

// ---------------- K2: 4 rows per block ----------------
__global__ __launch_bounds__(256) void k2_qkv(
        const float* __restrict__ pose_feat, const float* __restrict__ rgb,
        const float* __restrict__ pose_init, const float* __restrict__ in_b,
        const float* __restrict__ WqT, const float* __restrict__ mowT,
        const float* __restrict__ mob, const float* __restrict__ pe_gauss,
        const float* __restrict__ off_w1, const float* __restrict__ off_b1,
        const float* __restrict__ off_w2,
        const float* __restrict__ qwT, const float* __restrict__ kwT,
        const float* __restrict__ vwT,
        const float* __restrict__ kx, const float* __restrict__ vx,
        float* __restrict__ qT, float* __restrict__ kTt, float* __restrict__ vT,
        float* __restrict__ vgrid_g) {
    int b = blockIdx.x >> 6;
    int n0 = (blockIdx.x & 63) * 4;
    int t = threadIdx.x;
    __shared__ __align__(16) float xs[4][DIMC];
    __shared__ __align__(16) float qxs[4][DIMC];
    __shared__ __align__(16) float ctx[4][DIMC];
    __shared__ __align__(16) float x2[4][DIMC];
    __shared__ float lg[4][128], psm[4][128];
    __shared__ float qls[4][INNER];
    __shared__ float kvs[4][DIMC];
    __shared__ float vg[4][GROUPS][2];
    __shared__ float g01[4][2];

    if (t < 8) {
        int r = t >> 1, comp = t & 1;
        g01[r][comp] = 2.f * pose_init[(b * 2 + comp) * NQ + n0 + r] - 1.f;
    }
    float4 pf4 = *(const float4*)(pose_feat + (b * DIMC + t) * NQ + n0);
    float pfv[4] = {pf4.x, pf4.y, pf4.z, pf4.w};
    __syncthreads();
    {
        int j = t & 127;
        float pj0 = pe_gauss[j], pj1 = pe_gauss[128 + j];
        #pragma unroll
        for (int r = 0; r < 4; ++r) {
            float cc = (g01[r][0] * pj0 + g01[r][1] * pj1) * 6.28318530717958648f;
            float sc = (t < 128) ? sinf(cc) : cosf(cc);
            xs[r][t] = pfv[r] + sc;
        }
    }
    __syncthreads();
    {
        float bq = in_b[t];
        float a0 = bq, a1 = bq, a2 = bq, a3 = bq;
        #pragma unroll 2
        for (int d4 = 0; d4 < 64; ++d4) {
            int d = d4 * 4;
            float w0 = WqT[(d + 0) * DIMC + t];
            float w1 = WqT[(d + 1) * DIMC + t];
            float w2 = WqT[(d + 2) * DIMC + t];
            float w3 = WqT[(d + 3) * DIMC + t];
            float4 x0 = *(const float4*)&xs[0][d];
            float4 x1 = *(const float4*)&xs[1][d];
            float4 x2_ = *(const float4*)&xs[2][d];
            float4 x3 = *(const float4*)&xs[3][d];
            a0 = fmaf(w0, x0.x, a0); a0 = fmaf(w1, x0.y, a0); a0 = fmaf(w2, x0.z, a0); a0 = fmaf(w3, x0.w, a0);
            a1 = fmaf(w0, x1.x, a1); a1 = fmaf(w1, x1.y, a1); a1 = fmaf(w2, x1.z, a1); a1 = fmaf(w3, x1.w, a1);
            a2 = fmaf(w0, x2_.x, a2); a2 = fmaf(w1, x2_.y, a2); a2 = fmaf(w2, x2_.z, a2); a2 = fmaf(w3, x2_.w, a2);
            a3 = fmaf(w0, x3.x, a3); a3 = fmaf(w1, x3.y, a3); a3 = fmaf(w2, x3.z, a3); a3 = fmaf(w3, x3.w, a3);
        }
        qxs[0][t] = a0; qxs[1][t] = a1; qxs[2][t] = a2; qxs[3][t] = a3;
    }
    __syncthreads();
    #pragma unroll
    for (int rep = 0; rep < 2; ++rep) {
        int idx = rep * 256 + t;
        int r = idx >> 7, hh = (idx >> 4) & 7, tt = idx & 15;
        const float4* kp = (const float4*)(kx + (b * HWT + tt) * DIMC + hh * HDX);
        const float4* qp = (const float4*)(&qxs[r][hh * HDX]);
        float a = 0.f;
        #pragma unroll
        for (int d4 = 0; d4 < 8; ++d4) {
            float4 k4 = kp[d4], q4 = qp[d4];
            a = fmaf(q4.x, k4.x, a); a = fmaf(q4.y, k4.y, a);
            a = fmaf(q4.z, k4.z, a); a = fmaf(q4.w, k4.w, a);
        }
        lg[r][hh * 16 + tt] = a * 0.17677669529663689f;
    }
    __syncthreads();
    if (t < 32) {
        int r = t >> 3, hh = t & 7;
        float m = -1e30f;
        for (int tt = 0; tt < 16; ++tt) m = fmaxf(m, lg[r][hh * 16 + tt]);
        float s = 0.f;
        for (int tt = 0; tt < 16; ++tt) {
            float e = __expf(lg[r][hh * 16 + tt] - m);
            psm[r][hh * 16 + tt] = e; s += e;
        }
        float rr = 1.f / s;
        for (int tt = 0; tt < 16; ++tt) psm[r][hh * 16 + tt] *= rr;
    }
    __syncthreads();
    {
        int hh = t >> 5;
        const float* vp = vx + b * HWT * DIMC + t;
        float a0 = 0.f, a1 = 0.f, a2 = 0.f, a3 = 0.f;
        #pragma unroll
        for (int tt = 0; tt < 16; ++tt) {
            float vv = vp[tt * DIMC];
            a0 = fmaf(psm[0][hh * 16 + tt], vv, a0);
            a1 = fmaf(psm[1][hh * 16 + tt], vv, a1);
            a2 = fmaf(psm[2][hh * 16 + tt], vv, a2);
            a3 = fmaf(psm[3][hh * 16 + tt], vv, a3);
        }
        ctx[0][t] = a0; ctx[1][t] = a1; ctx[2][t] = a2; ctx[3][t] = a3;
    }
    __syncthreads();
    {
        float bm = mob[t];
        float a0 = bm, a1 = bm, a2 = bm, a3 = bm;
        #pragma unroll 2
        for (int d4 = 0; d4 < 64; ++d4) {
            int d = d4 * 4;
            float w0 = mowT[(d + 0) * DIMC + t];
            float w1 = mowT[(d + 1) * DIMC + t];
            float w2 = mowT[(d + 2) * DIMC + t];
            float w3 = mowT[(d + 3) * DIMC + t];
            float4 c0 = *(const float4*)&ctx[0][d];
            float4 c1 = *(const float4*)&ctx[1][d];
            float4 c2 = *(const float4*)&ctx[2][d];
            float4 c3 = *(const float4*)&ctx[3][d];
            a0 = fmaf(w0, c0.x, a0); a0 = fmaf(w1, c0.y, a0); a0 = fmaf(w2, c0.z, a0); a0 = fmaf(w3, c0.w, a0);
            a1 = fmaf(w0, c1.x, a1); a1 = fmaf(w1, c1.y, a1); a1 = fmaf(w2, c1.z, a1); a1 = fmaf(w3, c1.w, a1);
            a2 = fmaf(w0, c2.x, a2); a2 = fmaf(w1, c2.y, a2); a2 = fmaf(w2, c2.z, a2); a2 = fmaf(w3, c2.w, a2);
            a3 = fmaf(w0, c3.x, a3); a3 = fmaf(w1, c3.y, a3); a3 = fmaf(w2, c3.z, a3); a3 = fmaf(w3, c3.w, a3);
        }
        x2[0][t] = pfv[0] + a0; x2[1][t] = pfv[1] + a1;
        x2[2][t] = pfv[2] + a2; x2[3][t] = pfv[3] + a3;
    }
    __syncthreads();
    #pragma unroll
    for (int rep = 0; rep < 2; ++rep) {
        int ch = rep * 256 + t;
        int g = ch >> 6;
        float aq[4] = {0.f, 0.f, 0.f, 0.f};
        #pragma unroll
        for (int ci = 0; ci < 32; ++ci) {
            float w = qwT[ci * INNER + ch];
            aq[0] = fmaf(w, x2[0][g * 32 + ci], aq[0]);
            aq[1] = fmaf(w, x2[1][g * 32 + ci], aq[1]);
            aq[2] = fmaf(w, x2[2][g * 32 + ci], aq[2]);
            aq[3] = fmaf(w, x2[3][g * 32 + ci], aq[3]);
        }
        #pragma unroll
        for (int r = 0; r < 4; ++r) {
            qls[r][ch] = aq[r];
            qT[(b * NQ + n0 + r) * INNER + ch] = aq[r];
        }
    }
    __syncthreads();
    {
        int pr = t >> 3, l = t & 7;
        int r = pr >> 3, g = pr & 7;
        float s0 = 0.f, s1 = 0.f;
        #pragma unroll
        for (int e = 0; e < 8; ++e) {
            int jj = l * 8 + e;
            float ev = gelu_exact(fmaf(qls[r][g * 64 + jj], off_w1[jj], off_b1[jj]));
            s0 = fmaf(ev, off_w2[jj], s0);
            s1 = fmaf(ev, off_w2[64 + jj], s1);
        }
        #pragma unroll
        for (int o = 4; o > 0; o >>= 1) {
            s0 += __shfl_xor(s0, o, 64);
            s1 += __shfl_xor(s1, o, 64);
        }
        if (l == 0) {
            float vgx = g01[r][0] + tanhf(s0) * (2.f / 3.f);
            float vgy = g01[r][1] + tanhf(s1) * (2.f / 3.f);
            vg[r][g][0] = vgx; vg[r][g][1] = vgy;
            float* vp = vgrid_g + ((b * GROUPS + g) * NQ + n0 + r) * 2;
            vp[0] = vgx; vp[1] = vgy;
        }
    }
    __syncthreads();
    #pragma unroll
    for (int rep = 0; rep < 4; ++rep) {
        int idx = rep * 256 + t;
        int r = idx >> 8, c = idx & 255, g = c >> 5;
        float x = (vg[r][g][0] + 1.f) * 2.f - 0.5f;
        float y = (vg[r][g][1] + 1.f) * 2.f - 0.5f;
        float x0f = floorf(x), y0f = floorf(y);
        float wx = x - x0f, wy = y - y0f;
        int x0 = (int)x0f, y0 = (int)y0f;
        const float* img = rgb + (b * DIMC + c) * HWT;
        float v00 = samp4(img, y0, x0), v01 = samp4(img, y0, x0 + 1);
        float v10 = samp4(img, y0 + 1, x0), v11 = samp4(img, y0 + 1, x0 + 1);
        kvs[r][c] = v00 * (1.f - wx) * (1.f - wy) + v01 * wx * (1.f - wy)
                  + v10 * (1.f - wx) * wy + v11 * wx * wy;
    }
    __syncthreads();
    // grouped k/v convs; K transposed [bg][d][n], V row-major [b][n][inner]
    #pragma unroll
    for (int rep = 0; rep < 2; ++rep) {
        int ch = rep * 256 + t;
        int g = ch >> 6;
        float ak[4] = {0.f, 0.f, 0.f, 0.f};
        float av[4] = {0.f, 0.f, 0.f, 0.f};
        #pragma unroll
        for (int ci = 0; ci < 32; ++ci) {
            float wk = kwT[ci * INNER + ch];
            float wv = vwT[ci * INNER + ch];
            #pragma unroll
            for (int r = 0; r < 4; ++r) {
                float x = kvs[r][g * 32 + ci];
                ak[r] = fmaf(wk, x, ak[r]);
                av[r] = fmaf(wv, x, av[r]);
            }
        }
        int hh = ch >> 6, dh = ch & 63;
        float4 kk; kk.x = ak[0]; kk.y = ak[1]; kk.z = ak[2]; kk.w = ak[3];
        *(float4*)(kTt + ((b * HEADS + hh) * DH + dh) * NQ + n0) = kk;
        #pragma unroll
        for (int r = 0; r < 4; ++r)
            vT[(b * NQ + n0 + r) * INNER + ch] = av[r];
    }
}

// ---------------- K3a: CPB bias via fp16 MFMA, 8-waves/SIMD version ----------------
// grid 4096: blockIdx = ((bg*16 + jt)*8 + itc); wave: 4 j, 2 i-tiles of 16.
// __launch_bounds__(256,8) caps VGPR at 64 (occupancy cliff at 64 per m69).
// Live-state trimmed: accs processed in 2 passes (8 regs), b0 in LDS.
__global__ __launch_bounds__(256, 8) void k3a_bias(
        const float* __restrict__ pose_init, const float* __restrict__ vgrid_g,
        const float* __restrict__ w0, const float* __restrict__ b0,
        const float* __restrict__ b1, const float* __restrict__ w1,
        const float* __restrict__ w2, const float* __restrict__ b2,
        ushort_t* __restrict__ bias) {
    int bg = blockIdx.x >> 7;
    int jt = (blockIdx.x >> 3) & 15;
    int itc = blockIdx.x & 7;
    int b = bg >> 3;
    int tid = threadIdx.x;
    int wv = tid >> 6, lane = tid & 63;
    int lgp = lane >> 4, lr = lane & 15;

    __shared__ float gx_s[32], gy_s[32];
    __shared__ float2 b1w2_s[64];
    __shared__ float2 vg_s[16];
    __shared__ unsigned b0_lds[4][8];   // [lgp][kc*4+e2] packed fp16 pairs
    if (tid < 32) {
        int i = itc * 32 + tid;
        gx_s[tid] = 2.f * pose_init[(b * 2 + 0) * NQ + i] - 1.f;
        gy_s[tid] = 2.f * pose_init[(b * 2 + 1) * NQ + i] - 1.f;
    } else if (tid >= 64 && tid < 128) {
        int c2 = tid - 64;
        float2 bw; bw.x = b1[c2]; bw.y = w2[c2];
        b1w2_s[c2] = bw;
    } else if (tid >= 128 && tid < 144) {
        int j = jt * 16 + (tid - 128);
        vg_s[tid - 128] = ((const float2*)vgrid_g)[bg * NQ + j];
    } else if (tid >= 160 && tid < 192) {
        int idx = tid - 160;
        int lg2 = idx >> 3, rem = idx & 7, kc = rem >> 2, e2 = rem & 3;
        int c = kc * 32 + lg2 * 8 + 2 * e2;
        b0_lds[lg2][kc * 4 + e2] = pkrtz(b0[c], b0[c + 1]);
    }
    __syncthreads();

    // layer-0 weights as packed fp16 pairs (k = kc*32 + lgp*8 + 2*e2 {+1})
    unsigned w0a_pk[2][4], w0b_pk[2][4];
    #pragma unroll
    for (int kc = 0; kc < 2; ++kc)
        #pragma unroll
        for (int e2 = 0; e2 < 4; ++e2) {
            int c = kc * 32 + lgp * 8 + 2 * e2;
            w0a_pk[kc][e2] = pkrtz(w0[2 * c],     w0[2 * (c + 1)]);
            w0b_pk[kc][e2] = pkrtz(w0[2 * c + 1], w0[2 * (c + 1) + 1]);
        }
    // w1 as fp16 A-fragment: row c2 = nt*16 + lr, k = kc*32 + lgp*8 + e
    half8v bw1[2][4];
    #pragma unroll
    for (int nt = 0; nt < 4; ++nt) {
        int c2 = nt * 16 + lr;
        #pragma unroll
        for (int kc = 0; kc < 2; ++kc) {
            union { half8v v; unsigned u[4]; } tmp;
            #pragma unroll
            for (int e2 = 0; e2 < 4; ++e2) {
                int kk = kc * 32 + lgp * 8 + 2 * e2;
                tmp.u[e2] = pkrtz(w1[c2 * 64 + kk], w1[c2 * 64 + kk + 1]);
            }
            bw1[kc][nt] = tmp.v;
        }
    }
    float b2v = b2[0];
    ushort_t* brow_base = bias + bg * NQ * NQ;

    #pragma unroll 1
    for (int it2 = 0; it2 < 2; ++it2) {
        int it = itc * 2 + it2;
        float gxi = gx_s[it2 * 16 + lr], gyi = gy_s[it2 * 16 + lr];
        #pragma unroll 1
        for (int jj = 0; jj < 4; ++jj) {
            int jl = wv * 4 + jj;
            int j = jt * 16 + jl;
            float2 vgv = vg_s[jl];
            float px = gxi - vgv.x, py = gyi - vgv.y;
            float u = copysignf(__logf(1.f + fabsf(px)), px);
            float vvl = copysignf(__logf(1.f + fabsf(py)), py);
            unsigned uu = pkrtz(u, u);
            unsigned vv2 = pkrtz(vvl, vvl);
            // B-fragment: h0 = relu(w0a*u + w0b*v + b0), packed fp16 pairs
            union { half8v v; unsigned u[4]; } hb0u, hb1u;
            #pragma unroll
            for (int e2 = 0; e2 < 4; ++e2) {
                unsigned t0 = pk_fma_f16(w0b_pk[0][e2], vv2, b0_lds[lgp][e2]);
                unsigned h0 = pk_fma_f16(w0a_pk[0][e2], uu, t0);
                hb0u.u[e2] = pk_max0_f16(h0);
                unsigned t1 = pk_fma_f16(w0b_pk[1][e2], vv2, b0_lds[lgp][4 + e2]);
                unsigned h1 = pk_fma_f16(w0a_pk[1][e2], uu, t1);
                hb1u.u[e2] = pk_max0_f16(h1);
            }
            float s = 0.f;
            // pass 1: c2 tiles 0,1
            {
                f32x4 accA = {0.f, 0.f, 0.f, 0.f};
                f32x4 accB = {0.f, 0.f, 0.f, 0.f};
                accA = __builtin_amdgcn_mfma_f32_16x16x32_f16(bw1[0][0], hb0u.v, accA, 0, 0, 0);
                accA = __builtin_amdgcn_mfma_f32_16x16x32_f16(bw1[1][0], hb1u.v, accA, 0, 0, 0);
                accB = __builtin_amdgcn_mfma_f32_16x16x32_f16(bw1[0][1], hb0u.v, accB, 0, 0, 0);
                accB = __builtin_amdgcn_mfma_f32_16x16x32_f16(bw1[1][1], hb1u.v, accB, 0, 0, 0);
                #pragma unroll
                for (int r = 0; r < 4; ++r) {
                    float2 bwA = b1w2_s[0 * 16 + 4 * lgp + r];
                    float2 bwB = b1w2_s[1 * 16 + 4 * lgp + r];
                    s += fmaxf(accA[r] + bwA.x, 0.f) * bwA.y;
                    s += fmaxf(accB[r] + bwB.x, 0.f) * bwB.y;
                }
            }
            // pass 2: c2 tiles 2,3 (reuse acc regs)
            {
                f32x4 accA = {0.f, 0.f, 0.f, 0.f};
                f32x4 accB = {0.f, 0.f, 0.f, 0.f};
                accA = __builtin_amdgcn_mfma_f32_16x16x32_f16(bw1[0][2], hb0u.v, accA, 0, 0, 0);
                accA = __builtin_amdgcn_mfma_f32_16x16x32_f16(bw1[1][2], hb1u.v, accA, 0, 0, 0);
                accB = __builtin_amdgcn_mfma_f32_16x16x32_f16(bw1[0][3], hb0u.v, accB, 0, 0, 0);
                accB = __builtin_amdgcn_mfma_f32_16x16x32_f16(bw1[1][3], hb1u.v, accB, 0, 0, 0);
                #pragma unroll
                for (int r = 0; r < 4; ++r) {
                    float2 bwA = b1w2_s[2 * 16 + 4 * lgp + r];
                    float2 bwB = b1w2_s[3 * 16 + 4 * lgp + r];
                    s += fmaxf(accA[r] + bwA.x, 0.f) * bwA.y;
                    s += fmaxf(accB[r] + bwB.x, 0.f) * bwB.y;
                }
            }
            s += __shfl_xor(s, 16, 64);
            s += __shfl_xor(s, 32, 64);
            if (lane < 16)
                brow_base[(it * 16 + lr) * NQ + j] = (ushort_t)f2bf(s + b2v);
        }
    }
}

// ---------------- K3b: sim + bias + softmax + attn@V ----------------
__global__ __launch_bounds__(256) void k3b_attn(
        const float* __restrict__ qT, const float* __restrict__ kTt,
        const float* __restrict__ vT, const ushort_t* __restrict__ bias,
        float* __restrict__ aoT) {
    int bg = blockIdx.x >> 5;
    int itile = blockIdx.x & 31;
    int b = bg >> 3, h = bg & 7;
    int i0 = itile * 8;
    int tid = threadIdx.x;

    __shared__ __align__(16) float q_s[8][64];
    __shared__ __align__(16) float attn_s[8][NQ];
    __shared__ float ssum_s[8];

    for (int idx = tid; idx < 8 * 64; idx += 256) {
        int i = idx >> 6, d = idx & 63;
        q_s[i][d] = qT[(b * NQ + i0 + i) * INNER + h * 64 + d] * 0.125f;
    }
    __syncthreads();

    {
        int jq = tid & 63, ih = tid >> 6;
        const float4* kb4 = (const float4*)(kTt + bg * DH * NQ) + jq;
        float4 s0 = {0.f, 0.f, 0.f, 0.f};
        float4 s1 = {0.f, 0.f, 0.f, 0.f};
        #pragma unroll 4
        for (int d = 0; d < 64; ++d) {
            float4 kv = kb4[d * 64];
            float q0 = q_s[ih][d], q1 = q_s[ih + 4][d];
            s0.x = fmaf(q0, kv.x, s0.x); s0.y = fmaf(q0, kv.y, s0.y);
            s0.z = fmaf(q0, kv.z, s0.z); s0.w = fmaf(q0, kv.w, s0.w);
            s1.x = fmaf(q1, kv.x, s1.x); s1.y = fmaf(q1, kv.y, s1.y);
            s1.z = fmaf(q1, kv.z, s1.z); s1.w = fmaf(q1, kv.w, s1.w);
        }
        uint2 bb0 = *(const uint2*)(bias + (bg * NQ + i0 + ih) * NQ + jq * 4);
        uint2 bb1 = *(const uint2*)(bias + (bg * NQ + i0 + ih + 4) * NQ + jq * 4);
        s0.x += bf2f(bb0.x & 0xffffu); s0.y += bf2f(bb0.x >> 16);
        s0.z += bf2f(bb0.y & 0xffffu); s0.w += bf2f(bb0.y >> 16);
        s1.x += bf2f(bb1.x & 0xffffu); s1.y += bf2f(bb1.x >> 16);
        s1.z += bf2f(bb1.y & 0xffffu); s1.w += bf2f(bb1.y >> 16);
        *(float4*)&attn_s[ih][jq * 4] = s0;
        *(float4*)&attn_s[ih + 4][jq * 4] = s1;
    }
    __syncthreads();
    {
        int il = tid >> 5, lane = tid & 31;
        float m = -1e30f;
        for (int jj = 0; jj < 8; ++jj) m = fmaxf(m, attn_s[il][jj * 32 + lane]);
        #pragma unroll
        for (int o = 16; o > 0; o >>= 1) m = fmaxf(m, __shfl_xor(m, o, 32));
        float s = 0.f;
        for (int jj = 0; jj < 8; ++jj) {
            int j = jj * 32 + lane;
            float e = __expf(attn_s[il][j] - m);
            attn_s[il][j] = e;
            s += e;
        }
        #pragma unroll
        for (int o = 16; o > 0; o >>= 1) s += __shfl_xor(s, o, 32);
        if (lane == 0) ssum_s[il] = s;
    }
    __syncthreads();
    {
        int lane = tid & 31, il = tid >> 5;
        const float2* vp = (const float2*)(vT + b * NQ * INNER + h * 64) + lane;
        float a0 = 0.f, a1 = 0.f, c0 = 0.f, c1 = 0.f;
        #pragma unroll 4
        for (int j = 0; j < NQ; j += 2) {
            float w0 = attn_s[il][j], w1 = attn_s[il][j + 1];
            float2 v0 = vp[j * (INNER / 2)];
            float2 v1 = vp[(j + 1) * (INNER / 2)];
            a0 = fmaf(w0, v0.x, a0); a1 = fmaf(w0, v0.y, a1);
            c0 = fmaf(w1, v1.x, c0); c1 = fmaf(w1, v1.y, c1);
        }
        float r = 1.f / ssum_s[il];
        float2 res; res.x = (a0 + c0) * r; res.y = (a1 + c1) * r;
        *(float2*)(aoT + (b * NQ + i0 + il) * INNER + h * 64 + lane * 2) = res;
    }
}

// ---------------- K4: final projection 512 -> 256 (coalesced owT) ----------------
__global__ __launch_bounds__(256) void k4_proj(const float* __restrict__ aoT,
        const float* __restrict__ owT, const float* __restrict__ out_b,
        float* __restrict__ out) {
    int b = blockIdx.x >> 6;
    int n0 = (blockIdx.x & 63) * 4;
    int t = threadIdx.x;
    __shared__ __align__(16) float xl[4][INNER];
    for (int idx = t; idx < 4 * INNER; idx += 256) {
        xl[idx >> 9][idx & 511] = aoT[(b * NQ + n0) * INNER + idx];
    }
    __syncthreads();
    float bo = out_b[t];
    float a0 = bo, a1 = bo, a2 = bo, a3 = bo;
    #pragma unroll 2
    for (int c4 = 0; c4 < 128; ++c4) {
        int c = c4 * 4;
        float w0 = owT[(c + 0) * DIMC + t];
        float w1 = owT[(c + 1) * DIMC + t];
        float w2 = owT[(c + 2) * DIMC + t];
        float w3 = owT[(c + 3) * DIMC + t];
        float4 x0 = *(const float4*)&xl[0][c];
        float4 x1 = *(const float4*)&xl[1][c];
        float4 x2 = *(const float4*)&xl[2][c];
        float4 x3 = *(const float4*)&xl[3][c];
        a0 = fmaf(w0, x0.x, a0); a0 = fmaf(w1, x0.y, a0); a0 = fmaf(w2, x0.z, a0); a0 = fmaf(w3, x0.w, a0);
        a1 = fmaf(w0, x1.x, a1); a1 = fmaf(w1, x1.y, a1); a1 = fmaf(w2, x1.z, a1); a1 = fmaf(w3, x1.w, a1);
        a2 = fmaf(w0, x2.x, a2); a2 = fmaf(w1, x2.y, a2); a2 = fmaf(w2, x2.z, a2); a2 = fmaf(w3, x2.w, a2);
        a3 = fmaf(w0, x3.x, a3); a3 = fmaf(w1, x3.y, a3); a3 = fmaf(w2, x3.z, a3); a3 = fmaf(w3, x3.w, a3);
    }
    float4 res; res.x = a0; res.y = a1; res.z = a2; res.w = a3;
    *(float4*)(out + (b * DIMC + t) * NQ + n0) = res;
}

extern "C" void kernel_launch(void* const* d_in, const int* in_sizes, int n_in,
                              void* d_out, int out_size, void* d_ws, size_t ws_size,
                              hipStream_t stream) {
    const float* pose_feat = (const float*)d_in[0];
    const float* rgb       = (const float*)d_in[1];
    const float* pose_init = (const float*)d_in[2];
    const float* mha_in_w  = (const float*)d_in[3];
    const float* mha_in_b  = (const float*)d_in[4];
    const float* mha_out_w = (const float*)d_in[5];
    const float* mha_out_b = (const float*)d_in[6];
    const float* pe_gauss  = (const float*)d_in[7];
    const float* off_w1    = (const float*)d_in[8];
    const float* off_b1    = (const float*)d_in[9];
    const float* off_w2    = (const float*)d_in[10];
    const float* cpb_w0    = (const float*)d_in[11];
    const float* cpb_b0    = (const float*)d_in[12];
    const float* cpb_w1    = (const float*)d_in[13];
    const float* cpb_b1    = (const float*)d_in[14];
    const float* cpb_w2    = (const float*)d_in[15];
    const float* cpb_b2    = (const float*)d_in[16];
    const float* q_w       = (const float*)d_in[17];
    const float* k_w       = (const float*)d_in[18];
    const float* v_w       = (const float*)d_in[19];
    const float* out_w     = (const float*)d_in[20];
    const float* out_b     = (const float*)d_in[21];

    float* ws    = (float*)d_ws;
    float* kx    = ws;                     // 16384
    float* vx    = kx + 16384;             // 16384
    float* qT    = vx + 16384;             // 524288
    float* kTt   = qT + 524288;            // 524288
    float* vT    = kTt + 524288;           // 524288
    float* vgrid = vT + 524288;            // 16384
    float* aoT   = vgrid + 16384;          // 524288
    float* WqT   = aoT + 524288;           // 65536
    float* mowT  = WqT + 65536;            // 65536
    float* owT   = mowT + 65536;           // 131072
    float* qwT   = owT + 131072;           // 16384
    float* kwT   = qwT + 16384;            // 16384
    float* vwT   = kwT + 16384;            // 16384
    ushort_t* bias = (ushort_t*)(vwT + 16384);   // 32*256*256 bf16 = 4 MB
    float* out   = (float*)d_out;

    k0_tr<<<1216, 256, 0, stream>>>(mha_in_w, mha_out_w, out_w, q_w, k_w, v_w,
        WqT, mowT, owT, qwT, kwT, vwT);
    k1_kv<<<64, 256, 0, stream>>>(rgb, mha_in_w, mha_in_b, kx, vx);
    k2_qkv<<<256, 256, 0, stream>>>(pose_feat, rgb, pose_init, mha_in_b,
        WqT, mowT, mha_out_b, pe_gauss, off_w1, off_b1, off_w2, qwT, kwT, vwT,
        kx, vx, qT, kTt, vT, vgrid);
    k3a_bias<<<4096, 256, 0, stream>>>(pose_init, vgrid,
        cpb_w0, cpb_b0, cpb_b1, cpb_w1, cpb_w2, cpb_b2, bias);
    k3b_attn<<<1024, 256, 0, stream>>>(qT, kTt, vT, bias, aoT);
    k4_proj<<<256, 256, 0, stream>>>(aoT, owT, out_b, out);
}

// Round 15
// 174.494 us; speedup vs baseline: 1.6167x; 1.6167x over previous
//
#include <hip/hip_runtime.h>
#include <hip/hip_bf16.h>
#include <math.h>

// DeformableAttention2D — round 15: k3a 2-j ILP interleave. r14's forced
// 8-wave cap spilled to scratch (FETCH 390MB, 160us) -> reverted; kernel
// lives in the 4-wave/SIMD tier, so hide the ~280cy serial chain with two
// independent j-chains per iteration (shared weights, split acc passes).
// Sizes (fixed): B=4, N=256, DIM=256, HEADS=8, GROUPS=8, INNER=512, DH=64,
// cross-attn head dim 32, rgb 4x4 (16 tokens), CPB MLP 2->64->64->1.

#define DIMC 256
#define NQ 256
#define HEADS 8
#define GROUPS 8
#define INNER 512
#define DH 64
#define HDX 32
#define HWT 16

typedef __attribute__((ext_vector_type(8))) short short8v;
typedef __attribute__((ext_vector_type(8))) _Float16 half8v;
typedef __attribute__((ext_vector_type(4))) float f32x4;
typedef unsigned short ushort_t;

__device__ __forceinline__ float gelu_exact(float x) {
    return 0.5f * x * (1.f + erff(x * 0.70710678118654752f));
}
__device__ __forceinline__ short f2bf(float x) {
    union { float f; unsigned u; } c; c.f = x;
    unsigned r = c.u + 0x7fffu + ((c.u >> 16) & 1u);
    return (short)(r >> 16);
}
__device__ __forceinline__ float bf2f(unsigned hbits) {
    union { unsigned u; float f; } c; c.u = hbits << 16;
    return c.f;
}
__device__ __forceinline__ unsigned pkrtz(float a, float b) {
    auto h = __builtin_amdgcn_cvt_pkrtz(a, b);
    union { decltype(h) h2; unsigned u; } c; c.h2 = h; return c.u;
}
__device__ __forceinline__ unsigned pk_fma_f16(unsigned a, unsigned b, unsigned c) {
    unsigned d;
    asm("v_pk_fma_f16 %0, %1, %2, %3" : "=v"(d) : "v"(a), "v"(b), "v"(c));
    return d;
}
__device__ __forceinline__ unsigned pk_max0_f16(unsigned a) {
    unsigned d;
    asm("v_pk_max_f16 %0, %1, %2" : "=v"(d) : "v"(a), "v"(0u));
    return d;
}
__device__ __forceinline__ float samp4(const float* __restrict__ img, int yi, int xi) {
    bool valid = (xi >= 0) && (xi < 4) && (yi >= 0) && (yi < 4);
    int idx = min(max(yi, 0), 3) * 4 + min(max(xi, 0), 3);
    return valid ? img[idx] : 0.f;
}

// ---------------- K0: weight transposes ----------------
__global__ __launch_bounds__(256) void k0_tr(
        const float* __restrict__ in_w, const float* __restrict__ mow,
        const float* __restrict__ out_w, const float* __restrict__ q_w,
        const float* __restrict__ k_w, const float* __restrict__ v_w,
        float* __restrict__ WqT, float* __restrict__ mowT,
        float* __restrict__ owT, float* __restrict__ qwT,
        float* __restrict__ kwT, float* __restrict__ vwT) {
    int idx = blockIdx.x * 256 + threadIdx.x;
    if (idx < 65536) {
        int d = idx >> 8, o = idx & 255;
        WqT[idx] = in_w[o * 256 + d];
    } else if (idx < 131072) {
        int k = idx - 65536; int d = k >> 8, o = k & 255;
        mowT[k] = mow[o * 256 + d];
    } else if (idx < 262144) {
        int k = idx - 131072; int c = k >> 8, o = k & 255;
        owT[k] = out_w[o * 512 + c];
    } else if (idx < 278528) {
        int k = idx - 262144; int ci = k >> 9, ch = k & 511;
        qwT[k] = q_w[ch * 32 + ci];
    } else if (idx < 294912) {
        int k = idx - 278528; int ci = k >> 9, ch = k & 511;
        kwT[k] = k_w[ch * 32 + ci];
    } else if (idx < 311296) {
        int k = idx - 294912; int ci = k >> 9, ch = k & 511;
        vwT[k] = v_w[ch * 32 + ci];
    }
}

// ---------------- K1: kx, vx  [b,16,256] ----------------
__global__ __launch_bounds__(256) void k1_kv(const float* __restrict__ rgb,
        const float* __restrict__ in_w, const float* __restrict__ in_b,
        float* __restrict__ kx, float* __restrict__ vx) {
    int b = blockIdx.x >> 4;
    int tt = blockIdx.x & 15;
    int c = threadIdx.x;
    __shared__ __align__(16) float kvin[DIMC];
    float ang = (float)tt * powf(10000.f, -(float)(c >> 1) * (1.f / 128.f));
    float sv = (c & 1) ? cosf(ang) : sinf(ang);
    kvin[c] = rgb[(b * DIMC + c) * HWT + tt] + sv;
    __syncthreads();
    const float4* x4 = (const float4*)kvin;
    const float4* wk4 = (const float4*)(in_w + (DIMC + c) * DIMC);
    const float4* wv4 = (const float4*)(in_w + (2 * DIMC + c) * DIMC);
    float ak0 = in_b[DIMC + c], ak1 = 0.f, av0 = in_b[2 * DIMC + c], av1 = 0.f;
    #pragma unroll 4
    for (int d4 = 0; d4 < 64; ++d4) {
        float4 x = x4[d4], wk = wk4[d4], wv = wv4[d4];
        ak0 = fmaf(wk.x, x.x, ak0); ak1 = fmaf(wk.y, x.y, ak1);
        ak0 = fmaf(wk.z, x.z, ak0); ak1 = fmaf(wk.w, x.w, ak1);
        av0 = fmaf(wv.x, x.x, av0); av1 = fmaf(wv.y, x.y, av1);
        av0 = fmaf(wv.z, x.z, av0); av1 = fmaf(wv.w, x.w, av1);
    }
    kx[(b * HWT + tt) * DIMC + c] = ak0 + ak1;
    vx[(b * HWT + tt) * DIMC + c] = av0 + av1;
}

// ---------------- K2: 4 rows per block ----------------
__global__ __launch_bounds__(256) void k2_qkv(
        const float* __restrict__ pose_feat, const float* __restrict__ rgb,
        const float* __restrict__ pose_init, const float* __restrict__ in_b,
        const float* __restrict__ WqT, const float* __restrict__ mowT,
        const float* __restrict__ mob, const float* __restrict__ pe_gauss,
        const float* __restrict__ off_w1, const float* __restrict__ off_b1,
        const float* __restrict__ off_w2,
        const float* __restrict__ qwT, const float* __restrict__ kwT,
        const float* __restrict__ vwT,
        const float* __restrict__ kx, const float* __restrict__ vx,
        float* __restrict__ qT, float* __restrict__ kTt, float* __restrict__ vT,
        float* __restrict__ vgrid_g) {
    int b = blockIdx.x >> 6;
    int n0 = (blockIdx.x & 63) * 4;
    int t = threadIdx.x;
    __shared__ __align__(16) float xs[4][DIMC];
    __shared__ __align__(16) float qxs[4][DIMC];
    __shared__ __align__(16) float ctx[4][DIMC];
    __shared__ __align__(16) float x2[4][DIMC];
    __shared__ float lg[4][128], psm[4][128];
    __shared__ float qls[4][INNER];
    __shared__ float kvs[4][DIMC];
    __shared__ float vg[4][GROUPS][2];
    __shared__ float g01[4][2];

    if (t < 8) {
        int r = t >> 1, comp = t & 1;
        g01[r][comp] = 2.f * pose_init[(b * 2 + comp) * NQ + n0 + r] - 1.f;
    }
    float4 pf4 = *(const float4*)(pose_feat + (b * DIMC + t) * NQ + n0);
    float pfv[4] = {pf4.x, pf4.y, pf4.z, pf4.w};
    __syncthreads();
    {
        int j = t & 127;
        float pj0 = pe_gauss[j], pj1 = pe_gauss[128 + j];
        #pragma unroll
        for (int r = 0; r < 4; ++r) {
            float cc = (g01[r][0] * pj0 + g01[r][1] * pj1) * 6.28318530717958648f;
            float sc = (t < 128) ? sinf(cc) : cosf(cc);
            xs[r][t] = pfv[r] + sc;
        }
    }
    __syncthreads();
    {
        float bq = in_b[t];
        float a0 = bq, a1 = bq, a2 = bq, a3 = bq;
        #pragma unroll 2
        for (int d4 = 0; d4 < 64; ++d4) {
            int d = d4 * 4;
            float w0 = WqT[(d + 0) * DIMC + t];
            float w1 = WqT[(d + 1) * DIMC + t];
            float w2 = WqT[(d + 2) * DIMC + t];
            float w3 = WqT[(d + 3) * DIMC + t];
            float4 x0 = *(const float4*)&xs[0][d];
            float4 x1 = *(const float4*)&xs[1][d];
            float4 x2_ = *(const float4*)&xs[2][d];
            float4 x3 = *(const float4*)&xs[3][d];
            a0 = fmaf(w0, x0.x, a0); a0 = fmaf(w1, x0.y, a0); a0 = fmaf(w2, x0.z, a0); a0 = fmaf(w3, x0.w, a0);
            a1 = fmaf(w0, x1.x, a1); a1 = fmaf(w1, x1.y, a1); a1 = fmaf(w2, x1.z, a1); a1 = fmaf(w3, x1.w, a1);
            a2 = fmaf(w0, x2_.x, a2); a2 = fmaf(w1, x2_.y, a2); a2 = fmaf(w2, x2_.z, a2); a2 = fmaf(w3, x2_.w, a2);
            a3 = fmaf(w0, x3.x, a3); a3 = fmaf(w1, x3.y, a3); a3 = fmaf(w2, x3.z, a3); a3 = fmaf(w3, x3.w, a3);
        }
        qxs[0][t] = a0; qxs[1][t] = a1; qxs[2][t] = a2; qxs[3][t] = a3;
    }
    __syncthreads();
    #pragma unroll
    for (int rep = 0; rep < 2; ++rep) {
        int idx = rep * 256 + t;
        int r = idx >> 7, hh = (idx >> 4) & 7, tt = idx & 15;
        const float4* kp = (const float4*)(kx + (b * HWT + tt) * DIMC + hh * HDX);
        const float4* qp = (const float4*)(&qxs[r][hh * HDX]);
        float a = 0.f;
        #pragma unroll
        for (int d4 = 0; d4 < 8; ++d4) {
            float4 k4 = kp[d4], q4 = qp[d4];
            a = fmaf(q4.x, k4.x, a); a = fmaf(q4.y, k4.y, a);
            a = fmaf(q4.z, k4.z, a); a = fmaf(q4.w, k4.w, a);
        }
        lg[r][hh * 16 + tt] = a * 0.17677669529663689f;
    }
    __syncthreads();
    if (t < 32) {
        int r = t >> 3, hh = t & 7;
        float m = -1e30f;
        for (int tt = 0; tt < 16; ++tt) m = fmaxf(m, lg[r][hh * 16 + tt]);
        float s = 0.f;
        for (int tt = 0; tt < 16; ++tt) {
            float e = __expf(lg[r][hh * 16 + tt] - m);
            psm[r][hh * 16 + tt] = e; s += e;
        }
        float rr = 1.f / s;
        for (int tt = 0; tt < 16; ++tt) psm[r][hh * 16 + tt] *= rr;
    }
    __syncthreads();
    {
        int hh = t >> 5;
        const float* vp = vx + b * HWT * DIMC + t;
        float a0 = 0.f, a1 = 0.f, a2 = 0.f, a3 = 0.f;
        #pragma unroll
        for (int tt = 0; tt < 16; ++tt) {
            float vv = vp[tt * DIMC];
            a0 = fmaf(psm[0][hh * 16 + tt], vv, a0);
            a1 = fmaf(psm[1][hh * 16 + tt], vv, a1);
            a2 = fmaf(psm[2][hh * 16 + tt], vv, a2);
            a3 = fmaf(psm[3][hh * 16 + tt], vv, a3);
        }
        ctx[0][t] = a0; ctx[1][t] = a1; ctx[2][t] = a2; ctx[3][t] = a3;
    }
    __syncthreads();
    {
        float bm = mob[t];
        float a0 = bm, a1 = bm, a2 = bm, a3 = bm;
        #pragma unroll 2
        for (int d4 = 0; d4 < 64; ++d4) {
            int d = d4 * 4;
            float w0 = mowT[(d + 0) * DIMC + t];
            float w1 = mowT[(d + 1) * DIMC + t];
            float w2 = mowT[(d + 2) * DIMC + t];
            float w3 = mowT[(d + 3) * DIMC + t];
            float4 c0 = *(const float4*)&ctx[0][d];
            float4 c1 = *(const float4*)&ctx[1][d];
            float4 c2 = *(const float4*)&ctx[2][d];
            float4 c3 = *(const float4*)&ctx[3][d];
            a0 = fmaf(w0, c0.x, a0); a0 = fmaf(w1, c0.y, a0); a0 = fmaf(w2, c0.z, a0); a0 = fmaf(w3, c0.w, a0);
            a1 = fmaf(w0, c1.x, a1); a1 = fmaf(w1, c1.y, a1); a1 = fmaf(w2, c1.z, a1); a1 = fmaf(w3, c1.w, a1);
            a2 = fmaf(w0, c2.x, a2); a2 = fmaf(w1, c2.y, a2); a2 = fmaf(w2, c2.z, a2); a2 = fmaf(w3, c2.w, a2);
            a3 = fmaf(w0, c3.x, a3); a3 = fmaf(w1, c3.y, a3); a3 = fmaf(w2, c3.z, a3); a3 = fmaf(w3, c3.w, a3);
        }
        x2[0][t] = pfv[0] + a0; x2[1][t] = pfv[1] + a1;
        x2[2][t] = pfv[2] + a2; x2[3][t] = pfv[3] + a3;
    }
    __syncthreads();
    #pragma unroll
    for (int rep = 0; rep < 2; ++rep) {
        int ch = rep * 256 + t;
        int g = ch >> 6;
        float aq[4] = {0.f, 0.f, 0.f, 0.f};
        #pragma unroll
        for (int ci = 0; ci < 32; ++ci) {
            float w = qwT[ci * INNER + ch];
            aq[0] = fmaf(w, x2[0][g * 32 + ci], aq[0]);
            aq[1] = fmaf(w, x2[1][g * 32 + ci], aq[1]);
            aq[2] = fmaf(w, x2[2][g * 32 + ci], aq[2]);
            aq[3] = fmaf(w, x2[3][g * 32 + ci], aq[3]);
        }
        #pragma unroll
        for (int r = 0; r < 4; ++r) {
            qls[r][ch] = aq[r];
            qT[(b * NQ + n0 + r) * INNER + ch] = aq[r];
        }
    }
    __syncthreads();
    {
        int pr = t >> 3, l = t & 7;
        int r = pr >> 3, g = pr & 7;
        float s0 = 0.f, s1 = 0.f;
        #pragma unroll
        for (int e = 0; e < 8; ++e) {
            int jj = l * 8 + e;
            float ev = gelu_exact(fmaf(qls[r][g * 64 + jj], off_w1[jj], off_b1[jj]));
            s0 = fmaf(ev, off_w2[jj], s0);
            s1 = fmaf(ev, off_w2[64 + jj], s1);
        }
        #pragma unroll
        for (int o = 4; o > 0; o >>= 1) {
            s0 += __shfl_xor(s0, o, 64);
            s1 += __shfl_xor(s1, o, 64);
        }
        if (l == 0) {
            float vgx = g01[r][0] + tanhf(s0) * (2.f / 3.f);
            float vgy = g01[r][1] + tanhf(s1) * (2.f / 3.f);
            vg[r][g][0] = vgx; vg[r][g][1] = vgy;
            float* vp = vgrid_g + ((b * GROUPS + g) * NQ + n0 + r) * 2;
            vp[0] = vgx; vp[1] = vgy;
        }
    }
    __syncthreads();
    #pragma unroll
    for (int rep = 0; rep < 4; ++rep) {
        int idx = rep * 256 + t;
        int r = idx >> 8, c = idx & 255, g = c >> 5;
        float x = (vg[r][g][0] + 1.f) * 2.f - 0.5f;
        float y = (vg[r][g][1] + 1.f) * 2.f - 0.5f;
        float x0f = floorf(x), y0f = floorf(y);
        float wx = x - x0f, wy = y - y0f;
        int x0 = (int)x0f, y0 = (int)y0f;
        const float* img = rgb + (b * DIMC + c) * HWT;
        float v00 = samp4(img, y0, x0), v01 = samp4(img, y0, x0 + 1);
        float v10 = samp4(img, y0 + 1, x0), v11 = samp4(img, y0 + 1, x0 + 1);
        kvs[r][c] = v00 * (1.f - wx) * (1.f - wy) + v01 * wx * (1.f - wy)
                  + v10 * (1.f - wx) * wy + v11 * wx * wy;
    }
    __syncthreads();
    // grouped k/v convs; K transposed [bg][d][n], V row-major [b][n][inner]
    #pragma unroll
    for (int rep = 0; rep < 2; ++rep) {
        int ch = rep * 256 + t;
        int g = ch >> 6;
        float ak[4] = {0.f, 0.f, 0.f, 0.f};
        float av[4] = {0.f, 0.f, 0.f, 0.f};
        #pragma unroll
        for (int ci = 0; ci < 32; ++ci) {
            float wk = kwT[ci * INNER + ch];
            float wv = vwT[ci * INNER + ch];
            #pragma unroll
            for (int r = 0; r < 4; ++r) {
                float x = kvs[r][g * 32 + ci];
                ak[r] = fmaf(wk, x, ak[r]);
                av[r] = fmaf(wv, x, av[r]);
            }
        }
        int hh = ch >> 6, dh = ch & 63;
        float4 kk; kk.x = ak[0]; kk.y = ak[1]; kk.z = ak[2]; kk.w = ak[3];
        *(float4*)(kTt + ((b * HEADS + hh) * DH + dh) * NQ + n0) = kk;
        #pragma unroll
        for (int r = 0; r < 4; ++r)
            vT[(b * NQ + n0 + r) * INNER + ch] = av[r];
    }
}

// ---------------- K3a: CPB bias via fp16 MFMA, 2-j ILP interleave ----------------
// grid 4096: blockIdx = ((bg*16 + jt)*8 + itc); wave: 4 j (2 pairs), 2 i-tiles.
// mfma_f32_16x16x32_f16(A=w1, B=h0): C col (lane&15) = i, C row (4*lgp+reg)
// = c2. Two independent j-chains per body; acc tiles in 2 nt-passes.
__global__ __launch_bounds__(256) void k3a_bias(
        const float* __restrict__ pose_init, const float* __restrict__ vgrid_g,
        const float* __restrict__ w0, const float* __restrict__ b0,
        const float* __restrict__ b1, const float* __restrict__ w1,
        const float* __restrict__ w2, const float* __restrict__ b2,
        ushort_t* __restrict__ bias) {
    int bg = blockIdx.x >> 7;
    int jt = (blockIdx.x >> 3) & 15;
    int itc = blockIdx.x & 7;
    int b = bg >> 3;
    int tid = threadIdx.x;
    int wv = tid >> 6, lane = tid & 63;
    int lgp = lane >> 4, lr = lane & 15;

    __shared__ float gx_s[32], gy_s[32];
    __shared__ float2 b1w2_s[64];
    __shared__ float2 vg_s[16];
    __shared__ unsigned b0_lds[4][8];   // [lgp][kc*4+e2] packed fp16 pairs
    if (tid < 32) {
        int i = itc * 32 + tid;
        gx_s[tid] = 2.f * pose_init[(b * 2 + 0) * NQ + i] - 1.f;
        gy_s[tid] = 2.f * pose_init[(b * 2 + 1) * NQ + i] - 1.f;
    } else if (tid >= 64 && tid < 128) {
        int c2 = tid - 64;
        float2 bw; bw.x = b1[c2]; bw.y = w2[c2];
        b1w2_s[c2] = bw;
    } else if (tid >= 128 && tid < 144) {
        int j = jt * 16 + (tid - 128);
        vg_s[tid - 128] = ((const float2*)vgrid_g)[bg * NQ + j];
    } else if (tid >= 160 && tid < 192) {
        int idx = tid - 160;
        int lg2 = idx >> 3, rem = idx & 7, kc = rem >> 2, e2 = rem & 3;
        int c = kc * 32 + lg2 * 8 + 2 * e2;
        b0_lds[lg2][kc * 4 + e2] = pkrtz(b0[c], b0[c + 1]);
    }
    __syncthreads();

    // layer-0 weights as packed fp16 pairs (k = kc*32 + lgp*8 + 2*e2 {+1})
    unsigned w0a_pk[2][4], w0b_pk[2][4];
    #pragma unroll
    for (int kc = 0; kc < 2; ++kc)
        #pragma unroll
        for (int e2 = 0; e2 < 4; ++e2) {
            int c = kc * 32 + lgp * 8 + 2 * e2;
            w0a_pk[kc][e2] = pkrtz(w0[2 * c],     w0[2 * (c + 1)]);
            w0b_pk[kc][e2] = pkrtz(w0[2 * c + 1], w0[2 * (c + 1) + 1]);
        }
    // w1 as fp16 A-fragment: row c2 = nt*16 + lr, k = kc*32 + lgp*8 + e
    half8v w1f[2][4];
    #pragma unroll
    for (int nt = 0; nt < 4; ++nt) {
        int c2 = nt * 16 + lr;
        #pragma unroll
        for (int kc = 0; kc < 2; ++kc) {
            union { half8v v; unsigned u[4]; } tmp;
            #pragma unroll
            for (int e2 = 0; e2 < 4; ++e2) {
                int kk = kc * 32 + lgp * 8 + 2 * e2;
                tmp.u[e2] = pkrtz(w1[c2 * 64 + kk], w1[c2 * 64 + kk + 1]);
            }
            w1f[kc][nt] = tmp.v;
        }
    }
    float b2v = b2[0];
    ushort_t* brow_base = bias + bg * NQ * NQ;

    #pragma unroll 1
    for (int it2 = 0; it2 < 2; ++it2) {
        int it = itc * 2 + it2;
        float gxi = gx_s[it2 * 16 + lr], gyi = gy_s[it2 * 16 + lr];
        #pragma unroll 1
        for (int jp = 0; jp < 2; ++jp) {
            int jlA = wv * 4 + jp * 2;
            int jA = jt * 16 + jlA;
            float2 vgA = vg_s[jlA], vgB = vg_s[jlA + 1];
            float pxA = gxi - vgA.x, pyA = gyi - vgA.y;
            float pxB = gxi - vgB.x, pyB = gyi - vgB.y;
            float uA = copysignf(__logf(1.f + fabsf(pxA)), pxA);
            float vA = copysignf(__logf(1.f + fabsf(pyA)), pyA);
            float uB = copysignf(__logf(1.f + fabsf(pxB)), pxB);
            float vB = copysignf(__logf(1.f + fabsf(pyB)), pyB);
            unsigned uuA = pkrtz(uA, uA), vvA = pkrtz(vA, vA);
            unsigned uuB = pkrtz(uB, uB), vvB = pkrtz(vB, vB);
            // layer-0 for both j (independent chains)
            union { half8v v; unsigned u[4]; } hA0, hA1, hB0, hB1;
            #pragma unroll
            for (int e2 = 0; e2 < 4; ++e2) {
                hA0.u[e2] = pk_max0_f16(pk_fma_f16(w0a_pk[0][e2], uuA,
                              pk_fma_f16(w0b_pk[0][e2], vvA, b0_lds[lgp][e2])));
                hB0.u[e2] = pk_max0_f16(pk_fma_f16(w0a_pk[0][e2], uuB,
                              pk_fma_f16(w0b_pk[0][e2], vvB, b0_lds[lgp][e2])));
                hA1.u[e2] = pk_max0_f16(pk_fma_f16(w0a_pk[1][e2], uuA,
                              pk_fma_f16(w0b_pk[1][e2], vvA, b0_lds[lgp][4 + e2])));
                hB1.u[e2] = pk_max0_f16(pk_fma_f16(w0a_pk[1][e2], uuB,
                              pk_fma_f16(w0b_pk[1][e2], vvB, b0_lds[lgp][4 + e2])));
            }
            float sA = 0.f, sB = 0.f;
            #pragma unroll
            for (int ntp = 0; ntp < 2; ++ntp) {
                int n0t = 2 * ntp, n1t = 2 * ntp + 1;
                f32x4 aA0 = {0.f, 0.f, 0.f, 0.f};
                f32x4 aA1 = {0.f, 0.f, 0.f, 0.f};
                f32x4 aB0 = {0.f, 0.f, 0.f, 0.f};
                f32x4 aB1 = {0.f, 0.f, 0.f, 0.f};
                aA0 = __builtin_amdgcn_mfma_f32_16x16x32_f16(w1f[0][n0t], hA0.v, aA0, 0, 0, 0);
                aB0 = __builtin_amdgcn_mfma_f32_16x16x32_f16(w1f[0][n0t], hB0.v, aB0, 0, 0, 0);
                aA0 = __builtin_amdgcn_mfma_f32_16x16x32_f16(w1f[1][n0t], hA1.v, aA0, 0, 0, 0);
                aB0 = __builtin_amdgcn_mfma_f32_16x16x32_f16(w1f[1][n0t], hB1.v, aB0, 0, 0, 0);
                aA1 = __builtin_amdgcn_mfma_f32_16x16x32_f16(w1f[0][n1t], hA0.v, aA1, 0, 0, 0);
                aB1 = __builtin_amdgcn_mfma_f32_16x16x32_f16(w1f[0][n1t], hB0.v, aB1, 0, 0, 0);
                aA1 = __builtin_amdgcn_mfma_f32_16x16x32_f16(w1f[1][n1t], hA1.v, aA1, 0, 0, 0);
                aB1 = __builtin_amdgcn_mfma_f32_16x16x32_f16(w1f[1][n1t], hB1.v, aB1, 0, 0, 0);
                #pragma unroll
                for (int r = 0; r < 4; ++r) {
                    float2 bw0 = b1w2_s[n0t * 16 + 4 * lgp + r];
                    float2 bw1 = b1w2_s[n1t * 16 + 4 * lgp + r];
                    sA += fmaxf(aA0[r] + bw0.x, 0.f) * bw0.y;
                    sB += fmaxf(aB0[r] + bw0.x, 0.f) * bw0.y;
                    sA += fmaxf(aA1[r] + bw1.x, 0.f) * bw1.y;
                    sB += fmaxf(aB1[r] + bw1.x, 0.f) * bw1.y;
                }
            }
            sA += __shfl_xor(sA, 16, 64);
            sB += __shfl_xor(sB, 16, 64);
            sA += __shfl_xor(sA, 32, 64);
            sB += __shfl_xor(sB, 32, 64);
            if (lane < 16) {
                ushort_t* row = brow_base + (it * 16 + lr) * NQ + jA;
                row[0] = (ushort_t)f2bf(sA + b2v);
                row[1] = (ushort_t)f2bf(sB + b2v);
            }
        }
    }
}

// ---------------- K3b: sim + bias + softmax + attn@V ----------------
__global__ __launch_bounds__(256) void k3b_attn(
        const float* __restrict__ qT, const float* __restrict__ kTt,
        const float* __restrict__ vT, const ushort_t* __restrict__ bias,
        float* __restrict__ aoT) {
    int bg = blockIdx.x >> 5;
    int itile = blockIdx.x & 31;
    int b = bg >> 3, h = bg & 7;
    int i0 = itile * 8;
    int tid = threadIdx.x;

    __shared__ __align__(16) float q_s[8][64];
    __shared__ __align__(16) float attn_s[8][NQ];
    __shared__ float ssum_s[8];

    for (int idx = tid; idx < 8 * 64; idx += 256) {
        int i = idx >> 6, d = idx & 63;
        q_s[i][d] = qT[(b * NQ + i0 + i) * INNER + h * 64 + d] * 0.125f;
    }
    __syncthreads();

    {
        int jq = tid & 63, ih = tid >> 6;
        const float4* kb4 = (const float4*)(kTt + bg * DH * NQ) + jq;
        float4 s0 = {0.f, 0.f, 0.f, 0.f};
        float4 s1 = {0.f, 0.f, 0.f, 0.f};
        #pragma unroll 4
        for (int d = 0; d < 64; ++d) {
            float4 kv = kb4[d * 64];
            float q0 = q_s[ih][d], q1 = q_s[ih + 4][d];
            s0.x = fmaf(q0, kv.x, s0.x); s0.y = fmaf(q0, kv.y, s0.y);
            s0.z = fmaf(q0, kv.z, s0.z); s0.w = fmaf(q0, kv.w, s0.w);
            s1.x = fmaf(q1, kv.x, s1.x); s1.y = fmaf(q1, kv.y, s1.y);
            s1.z = fmaf(q1, kv.z, s1.z); s1.w = fmaf(q1, kv.w, s1.w);
        }
        uint2 bb0 = *(const uint2*)(bias + (bg * NQ + i0 + ih) * NQ + jq * 4);
        uint2 bb1 = *(const uint2*)(bias + (bg * NQ + i0 + ih + 4) * NQ + jq * 4);
        s0.x += bf2f(bb0.x & 0xffffu); s0.y += bf2f(bb0.x >> 16);
        s0.z += bf2f(bb0.y & 0xffffu); s0.w += bf2f(bb0.y >> 16);
        s1.x += bf2f(bb1.x & 0xffffu); s1.y += bf2f(bb1.x >> 16);
        s1.z += bf2f(bb1.y & 0xffffu); s1.w += bf2f(bb1.y >> 16);
        *(float4*)&attn_s[ih][jq * 4] = s0;
        *(float4*)&attn_s[ih + 4][jq * 4] = s1;
    }
    __syncthreads();
    {
        int il = tid >> 5, lane = tid & 31;
        float m = -1e30f;
        for (int jj = 0; jj < 8; ++jj) m = fmaxf(m, attn_s[il][jj * 32 + lane]);
        #pragma unroll
        for (int o = 16; o > 0; o >>= 1) m = fmaxf(m, __shfl_xor(m, o, 32));
        float s = 0.f;
        for (int jj = 0; jj < 8; ++jj) {
            int j = jj * 32 + lane;
            float e = __expf(attn_s[il][j] - m);
            attn_s[il][j] = e;
            s += e;
        }
        #pragma unroll
        for (int o = 16; o > 0; o >>= 1) s += __shfl_xor(s, o, 32);
        if (lane == 0) ssum_s[il] = s;
    }
    __syncthreads();
    {
        int lane = tid & 31, il = tid >> 5;
        const float2* vp = (const float2*)(vT + b * NQ * INNER + h * 64) + lane;
        float a0 = 0.f, a1 = 0.f, c0 = 0.f, c1 = 0.f;
        #pragma unroll 4
        for (int j = 0; j < NQ; j += 2) {
            float w0 = attn_s[il][j], w1 = attn_s[il][j + 1];
            float2 v0 = vp[j * (INNER / 2)];
            float2 v1 = vp[(j + 1) * (INNER / 2)];
            a0 = fmaf(w0, v0.x, a0); a1 = fmaf(w0, v0.y, a1);
            c0 = fmaf(w1, v1.x, c0); c1 = fmaf(w1, v1.y, c1);
        }
        float r = 1.f / ssum_s[il];
        float2 res; res.x = (a0 + c0) * r; res.y = (a1 + c1) * r;
        *(float2*)(aoT + (b * NQ + i0 + il) * INNER + h * 64 + lane * 2) = res;
    }
}

// ---------------- K4: final projection 512 -> 256 (coalesced owT) ----------------
__global__ __launch_bounds__(256) void k4_proj(const float* __restrict__ aoT,
        const float* __restrict__ owT, const float* __restrict__ out_b,
        float* __restrict__ out) {
    int b = blockIdx.x >> 6;
    int n0 = (blockIdx.x & 63) * 4;
    int t = threadIdx.x;
    __shared__ __align__(16) float xl[4][INNER];
    for (int idx = t; idx < 4 * INNER; idx += 256) {
        xl[idx >> 9][idx & 511] = aoT[(b * NQ + n0) * INNER + idx];
    }
    __syncthreads();
    float bo = out_b[t];
    float a0 = bo, a1 = bo, a2 = bo, a3 = bo;
    #pragma unroll 2
    for (int c4 = 0; c4 < 128; ++c4) {
        int c = c4 * 4;
        float w0 = owT[(c + 0) * DIMC + t];
        float w1 = owT[(c + 1) * DIMC + t];
        float w2 = owT[(c + 2) * DIMC + t];
        float w3 = owT[(c + 3) * DIMC + t];
        float4 x0 = *(const float4*)&xl[0][c];
        float4 x1 = *(const float4*)&xl[1][c];
        float4 x2 = *(const float4*)&xl[2][c];
        float4 x3 = *(const float4*)&xl[3][c];
        a0 = fmaf(w0, x0.x, a0); a0 = fmaf(w1, x0.y, a0); a0 = fmaf(w2, x0.z, a0); a0 = fmaf(w3, x0.w, a0);
        a1 = fmaf(w0, x1.x, a1); a1 = fmaf(w1, x1.y, a1); a1 = fmaf(w2, x1.z, a1); a1 = fmaf(w3, x1.w, a1);
        a2 = fmaf(w0, x2.x, a2); a2 = fmaf(w1, x2.y, a2); a2 = fmaf(w2, x2.z, a2); a2 = fmaf(w3, x2.w, a2);
        a3 = fmaf(w0, x3.x, a3); a3 = fmaf(w1, x3.y, a3); a3 = fmaf(w2, x3.z, a3); a3 = fmaf(w3, x3.w, a3);
    }
    float4 res; res.x = a0; res.y = a1; res.z = a2; res.w = a3;
    *(float4*)(out + (b * DIMC + t) * NQ + n0) = res;
}

extern "C" void kernel_launch(void* const* d_in, const int* in_sizes, int n_in,
                              void* d_out, int out_size, void* d_ws, size_t ws_size,
                              hipStream_t stream) {
    const float* pose_feat = (const float*)d_in[0];
    const float* rgb       = (const float*)d_in[1];
    const float* pose_init = (const float*)d_in[2];
    const float* mha_in_w  = (const float*)d_in[3];
    const float* mha_in_b  = (const float*)d_in[4];
    const float* mha_out_w = (const float*)d_in[5];
    const float* mha_out_b = (const float*)d_in[6];
    const float* pe_gauss  = (const float*)d_in[7];
    const float* off_w1    = (const float*)d_in[8];
    const float* off_b1    = (const float*)d_in[9];
    const float* off_w2    = (const float*)d_in[10];
    const float* cpb_w0    = (const float*)d_in[11];
    const float* cpb_b0    = (const float*)d_in[12];
    const float* cpb_w1    = (const float*)d_in[13];
    const float* cpb_b1    = (const float*)d_in[14];
    const float* cpb_w2    = (const float*)d_in[15];
    const float* cpb_b2    = (const float*)d_in[16];
    const float* q_w       = (const float*)d_in[17];
    const float* k_w       = (const float*)d_in[18];
    const float* v_w       = (const float*)d_in[19];
    const float* out_w     = (const float*)d_in[20];
    const float* out_b     = (const float*)d_in[21];

    float* ws    = (float*)d_ws;
    float* kx    = ws;                     // 16384
    float* vx    = kx + 16384;             // 16384
    float* qT    = vx + 16384;             // 524288
    float* kTt   = qT + 524288;            // 524288
    float* vT    = kTt + 524288;           // 524288
    float* vgrid = vT + 524288;            // 16384
    float* aoT   = vgrid + 16384;          // 524288
    float* WqT   = aoT + 524288;           // 65536
    float* mowT  = WqT + 65536;            // 65536
    float* owT   = mowT + 65536;           // 131072
    float* qwT   = owT + 131072;           // 16384
    float* kwT   = qwT + 16384;            // 16384
    float* vwT   = kwT + 16384;            // 16384
    ushort_t* bias = (ushort_t*)(vwT + 16384);   // 32*256*256 bf16 = 4 MB
    float* out   = (float*)d_out;

    k0_tr<<<1216, 256, 0, stream>>>(mha_in_w, mha_out_w, out_w, q_w, k_w, v_w,
        WqT, mowT, owT, qwT, kwT, vwT);
    k1_kv<<<64, 256, 0, stream>>>(rgb, mha_in_w, mha_in_b, kx, vx);
    k2_qkv<<<256, 256, 0, stream>>>(pose_feat, rgb, pose_init, mha_in_b,
        WqT, mowT, mha_out_b, pe_gauss, off_w1, off_b1, off_w2, qwT, kwT, vwT,
        kx, vx, qT, kTt, vT, vgrid);
    k3a_bias<<<4096, 256, 0, stream>>>(pose_init, vgrid,
        cpb_w0, cpb_b0, cpb_b1, cpb_w1, cpb_w2, cpb_b2, bias);
    k3b_attn<<<1024, 256, 0, stream>>>(qT, kTt, vT, bias, aoT);
    k4_proj<<<256, 256, 0, stream>>>(aoT, owT, out_b, out);
}

// Round 16
// 167.679 us; speedup vs baseline: 1.6824x; 1.0406x over previous
//
#include <hip/hip_runtime.h>
#include <hip/hip_bf16.h>
#include <math.h>

// DeformableAttention2D — round 16: k3a prologue amortization. Per-block
// weight-fragment prologue (~100 loads + 64 pkrtz) ~= body cost at grid
// 4096 x 4 iters; restructure to grid 1024 x 16 iters (4x amortization,
// whole grid co-resident at 4 blocks/CU). Body unchanged from r15.
// Sizes (fixed): B=4, N=256, DIM=256, HEADS=8, GROUPS=8, INNER=512, DH=64,
// cross-attn head dim 32, rgb 4x4 (16 tokens), CPB MLP 2->64->64->1.

#define DIMC 256
#define NQ 256
#define HEADS 8
#define GROUPS 8
#define INNER 512
#define DH 64
#define HDX 32
#define HWT 16

typedef __attribute__((ext_vector_type(8))) short short8v;
typedef __attribute__((ext_vector_type(8))) _Float16 half8v;
typedef __attribute__((ext_vector_type(4))) float f32x4;
typedef unsigned short ushort_t;

__device__ __forceinline__ float gelu_exact(float x) {
    return 0.5f * x * (1.f + erff(x * 0.70710678118654752f));
}
__device__ __forceinline__ short f2bf(float x) {
    union { float f; unsigned u; } c; c.f = x;
    unsigned r = c.u + 0x7fffu + ((c.u >> 16) & 1u);
    return (short)(r >> 16);
}
__device__ __forceinline__ float bf2f(unsigned hbits) {
    union { unsigned u; float f; } c; c.u = hbits << 16;
    return c.f;
}
__device__ __forceinline__ unsigned pkrtz(float a, float b) {
    auto h = __builtin_amdgcn_cvt_pkrtz(a, b);
    union { decltype(h) h2; unsigned u; } c; c.h2 = h; return c.u;
}
__device__ __forceinline__ unsigned pk_fma_f16(unsigned a, unsigned b, unsigned c) {
    unsigned d;
    asm("v_pk_fma_f16 %0, %1, %2, %3" : "=v"(d) : "v"(a), "v"(b), "v"(c));
    return d;
}
__device__ __forceinline__ unsigned pk_max0_f16(unsigned a) {
    unsigned d;
    asm("v_pk_max_f16 %0, %1, %2" : "=v"(d) : "v"(a), "v"(0u));
    return d;
}
__device__ __forceinline__ float samp4(const float* __restrict__ img, int yi, int xi) {
    bool valid = (xi >= 0) && (xi < 4) && (yi >= 0) && (yi < 4);
    int idx = min(max(yi, 0), 3) * 4 + min(max(xi, 0), 3);
    return valid ? img[idx] : 0.f;
}

// ---------------- K0: weight transposes ----------------
__global__ __launch_bounds__(256) void k0_tr(
        const float* __restrict__ in_w, const float* __restrict__ mow,
        const float* __restrict__ out_w, const float* __restrict__ q_w,
        const float* __restrict__ k_w, const float* __restrict__ v_w,
        float* __restrict__ WqT, float* __restrict__ mowT,
        float* __restrict__ owT, float* __restrict__ qwT,
        float* __restrict__ kwT, float* __restrict__ vwT) {
    int idx = blockIdx.x * 256 + threadIdx.x;
    if (idx < 65536) {
        int d = idx >> 8, o = idx & 255;
        WqT[idx] = in_w[o * 256 + d];
    } else if (idx < 131072) {
        int k = idx - 65536; int d = k >> 8, o = k & 255;
        mowT[k] = mow[o * 256 + d];
    } else if (idx < 262144) {
        int k = idx - 131072; int c = k >> 8, o = k & 255;
        owT[k] = out_w[o * 512 + c];
    } else if (idx < 278528) {
        int k = idx - 262144; int ci = k >> 9, ch = k & 511;
        qwT[k] = q_w[ch * 32 + ci];
    } else if (idx < 294912) {
        int k = idx - 278528; int ci = k >> 9, ch = k & 511;
        kwT[k] = k_w[ch * 32 + ci];
    } else if (idx < 311296) {
        int k = idx - 294912; int ci = k >> 9, ch = k & 511;
        vwT[k] = v_w[ch * 32 + ci];
    }
}

// ---------------- K1: kx, vx  [b,16,256] ----------------
__global__ __launch_bounds__(256) void k1_kv(const float* __restrict__ rgb,
        const float* __restrict__ in_w, const float* __restrict__ in_b,
        float* __restrict__ kx, float* __restrict__ vx) {
    int b = blockIdx.x >> 4;
    int tt = blockIdx.x & 15;
    int c = threadIdx.x;
    __shared__ __align__(16) float kvin[DIMC];
    float ang = (float)tt * powf(10000.f, -(float)(c >> 1) * (1.f / 128.f));
    float sv = (c & 1) ? cosf(ang) : sinf(ang);
    kvin[c] = rgb[(b * DIMC + c) * HWT + tt] + sv;
    __syncthreads();
    const float4* x4 = (const float4*)kvin;
    const float4* wk4 = (const float4*)(in_w + (DIMC + c) * DIMC);
    const float4* wv4 = (const float4*)(in_w + (2 * DIMC + c) * DIMC);
    float ak0 = in_b[DIMC + c], ak1 = 0.f, av0 = in_b[2 * DIMC + c], av1 = 0.f;
    #pragma unroll 4
    for (int d4 = 0; d4 < 64; ++d4) {
        float4 x = x4[d4], wk = wk4[d4], wv = wv4[d4];
        ak0 = fmaf(wk.x, x.x, ak0); ak1 = fmaf(wk.y, x.y, ak1);
        ak0 = fmaf(wk.z, x.z, ak0); ak1 = fmaf(wk.w, x.w, ak1);
        av0 = fmaf(wv.x, x.x, av0); av1 = fmaf(wv.y, x.y, av1);
        av0 = fmaf(wv.z, x.z, av0); av1 = fmaf(wv.w, x.w, av1);
    }
    kx[(b * HWT + tt) * DIMC + c] = ak0 + ak1;
    vx[(b * HWT + tt) * DIMC + c] = av0 + av1;
}

// ---------------- K2: 4 rows per block ----------------
__global__ __launch_bounds__(256) void k2_qkv(
        const float* __restrict__ pose_feat, const float* __restrict__ rgb,
        const float* __restrict__ pose_init, const float* __restrict__ in_b,
        const float* __restrict__ WqT, const float* __restrict__ mowT,
        const float* __restrict__ mob, const float* __restrict__ pe_gauss,
        const float* __restrict__ off_w1, const float* __restrict__ off_b1,
        const float* __restrict__ off_w2,
        const float* __restrict__ qwT, const float* __restrict__ kwT,
        const float* __restrict__ vwT,
        const float* __restrict__ kx, const float* __restrict__ vx,
        float* __restrict__ qT, float* __restrict__ kTt, float* __restrict__ vT,
        float* __restrict__ vgrid_g) {
    int b = blockIdx.x >> 6;
    int n0 = (blockIdx.x & 63) * 4;
    int t = threadIdx.x;
    __shared__ __align__(16) float xs[4][DIMC];
    __shared__ __align__(16) float qxs[4][DIMC];
    __shared__ __align__(16) float ctx[4][DIMC];
    __shared__ __align__(16) float x2[4][DIMC];
    __shared__ float lg[4][128], psm[4][128];
    __shared__ float qls[4][INNER];
    __shared__ float kvs[4][DIMC];
    __shared__ float vg[4][GROUPS][2];
    __shared__ float g01[4][2];

    if (t < 8) {
        int r = t >> 1, comp = t & 1;
        g01[r][comp] = 2.f * pose_init[(b * 2 + comp) * NQ + n0 + r] - 1.f;
    }
    float4 pf4 = *(const float4*)(pose_feat + (b * DIMC + t) * NQ + n0);
    float pfv[4] = {pf4.x, pf4.y, pf4.z, pf4.w};
    __syncthreads();
    {
        int j = t & 127;
        float pj0 = pe_gauss[j], pj1 = pe_gauss[128 + j];
        #pragma unroll
        for (int r = 0; r < 4; ++r) {
            float cc = (g01[r][0] * pj0 + g01[r][1] * pj1) * 6.28318530717958648f;
            float sc = (t < 128) ? sinf(cc) : cosf(cc);
            xs[r][t] = pfv[r] + sc;
        }
    }
    __syncthreads();
    {
        float bq = in_b[t];
        float a0 = bq, a1 = bq, a2 = bq, a3 = bq;
        #pragma unroll 2
        for (int d4 = 0; d4 < 64; ++d4) {
            int d = d4 * 4;
            float w0 = WqT[(d + 0) * DIMC + t];
            float w1 = WqT[(d + 1) * DIMC + t];
            float w2 = WqT[(d + 2) * DIMC + t];
            float w3 = WqT[(d + 3) * DIMC + t];
            float4 x0 = *(const float4*)&xs[0][d];
            float4 x1 = *(const float4*)&xs[1][d];
            float4 x2_ = *(const float4*)&xs[2][d];
            float4 x3 = *(const float4*)&xs[3][d];
            a0 = fmaf(w0, x0.x, a0); a0 = fmaf(w1, x0.y, a0); a0 = fmaf(w2, x0.z, a0); a0 = fmaf(w3, x0.w, a0);
            a1 = fmaf(w0, x1.x, a1); a1 = fmaf(w1, x1.y, a1); a1 = fmaf(w2, x1.z, a1); a1 = fmaf(w3, x1.w, a1);
            a2 = fmaf(w0, x2_.x, a2); a2 = fmaf(w1, x2_.y, a2); a2 = fmaf(w2, x2_.z, a2); a2 = fmaf(w3, x2_.w, a2);
            a3 = fmaf(w0, x3.x, a3); a3 = fmaf(w1, x3.y, a3); a3 = fmaf(w2, x3.z, a3); a3 = fmaf(w3, x3.w, a3);
        }
        qxs[0][t] = a0; qxs[1][t] = a1; qxs[2][t] = a2; qxs[3][t] = a3;
    }
    __syncthreads();
    #pragma unroll
    for (int rep = 0; rep < 2; ++rep) {
        int idx = rep * 256 + t;
        int r = idx >> 7, hh = (idx >> 4) & 7, tt = idx & 15;
        const float4* kp = (const float4*)(kx + (b * HWT + tt) * DIMC + hh * HDX);
        const float4* qp = (const float4*)(&qxs[r][hh * HDX]);
        float a = 0.f;
        #pragma unroll
        for (int d4 = 0; d4 < 8; ++d4) {
            float4 k4 = kp[d4], q4 = qp[d4];
            a = fmaf(q4.x, k4.x, a); a = fmaf(q4.y, k4.y, a);
            a = fmaf(q4.z, k4.z, a); a = fmaf(q4.w, k4.w, a);
        }
        lg[r][hh * 16 + tt] = a * 0.17677669529663689f;
    }
    __syncthreads();
    if (t < 32) {
        int r = t >> 3, hh = t & 7;
        float m = -1e30f;
        for (int tt = 0; tt < 16; ++tt) m = fmaxf(m, lg[r][hh * 16 + tt]);
        float s = 0.f;
        for (int tt = 0; tt < 16; ++tt) {
            float e = __expf(lg[r][hh * 16 + tt] - m);
            psm[r][hh * 16 + tt] = e; s += e;
        }
        float rr = 1.f / s;
        for (int tt = 0; tt < 16; ++tt) psm[r][hh * 16 + tt] *= rr;
    }
    __syncthreads();
    {
        int hh = t >> 5;
        const float* vp = vx + b * HWT * DIMC + t;
        float a0 = 0.f, a1 = 0.f, a2 = 0.f, a3 = 0.f;
        #pragma unroll
        for (int tt = 0; tt < 16; ++tt) {
            float vv = vp[tt * DIMC];
            a0 = fmaf(psm[0][hh * 16 + tt], vv, a0);
            a1 = fmaf(psm[1][hh * 16 + tt], vv, a1);
            a2 = fmaf(psm[2][hh * 16 + tt], vv, a2);
            a3 = fmaf(psm[3][hh * 16 + tt], vv, a3);
        }
        ctx[0][t] = a0; ctx[1][t] = a1; ctx[2][t] = a2; ctx[3][t] = a3;
    }
    __syncthreads();
    {
        float bm = mob[t];
        float a0 = bm, a1 = bm, a2 = bm, a3 = bm;
        #pragma unroll 2
        for (int d4 = 0; d4 < 64; ++d4) {
            int d = d4 * 4;
            float w0 = mowT[(d + 0) * DIMC + t];
            float w1 = mowT[(d + 1) * DIMC + t];
            float w2 = mowT[(d + 2) * DIMC + t];
            float w3 = mowT[(d + 3) * DIMC + t];
            float4 c0 = *(const float4*)&ctx[0][d];
            float4 c1 = *(const float4*)&ctx[1][d];
            float4 c2 = *(const float4*)&ctx[2][d];
            float4 c3 = *(const float4*)&ctx[3][d];
            a0 = fmaf(w0, c0.x, a0); a0 = fmaf(w1, c0.y, a0); a0 = fmaf(w2, c0.z, a0); a0 = fmaf(w3, c0.w, a0);
            a1 = fmaf(w0, c1.x, a1); a1 = fmaf(w1, c1.y, a1); a1 = fmaf(w2, c1.z, a1); a1 = fmaf(w3, c1.w, a1);
            a2 = fmaf(w0, c2.x, a2); a2 = fmaf(w1, c2.y, a2); a2 = fmaf(w2, c2.z, a2); a2 = fmaf(w3, c2.w, a2);
            a3 = fmaf(w0, c3.x, a3); a3 = fmaf(w1, c3.y, a3); a3 = fmaf(w2, c3.z, a3); a3 = fmaf(w3, c3.w, a3);
        }
        x2[0][t] = pfv[0] + a0; x2[1][t] = pfv[1] + a1;
        x2[2][t] = pfv[2] + a2; x2[3][t] = pfv[3] + a3;
    }
    __syncthreads();
    #pragma unroll
    for (int rep = 0; rep < 2; ++rep) {
        int ch = rep * 256 + t;
        int g = ch >> 6;
        float aq[4] = {0.f, 0.f, 0.f, 0.f};
        #pragma unroll
        for (int ci = 0; ci < 32; ++ci) {
            float w = qwT[ci * INNER + ch];
            aq[0] = fmaf(w, x2[0][g * 32 + ci], aq[0]);
            aq[1] = fmaf(w, x2[1][g * 32 + ci], aq[1]);
            aq[2] = fmaf(w, x2[2][g * 32 + ci], aq[2]);
            aq[3] = fmaf(w, x2[3][g * 32 + ci], aq[3]);
        }
        #pragma unroll
        for (int r = 0; r < 4; ++r) {
            qls[r][ch] = aq[r];
            qT[(b * NQ + n0 + r) * INNER + ch] = aq[r];
        }
    }
    __syncthreads();
    {
        int pr = t >> 3, l = t & 7;
        int r = pr >> 3, g = pr & 7;
        float s0 = 0.f, s1 = 0.f;
        #pragma unroll
        for (int e = 0; e < 8; ++e) {
            int jj = l * 8 + e;
            float ev = gelu_exact(fmaf(qls[r][g * 64 + jj], off_w1[jj], off_b1[jj]));
            s0 = fmaf(ev, off_w2[jj], s0);
            s1 = fmaf(ev, off_w2[64 + jj], s1);
        }
        #pragma unroll
        for (int o = 4; o > 0; o >>= 1) {
            s0 += __shfl_xor(s0, o, 64);
            s1 += __shfl_xor(s1, o, 64);
        }
        if (l == 0) {
            float vgx = g01[r][0] + tanhf(s0) * (2.f / 3.f);
            float vgy = g01[r][1] + tanhf(s1) * (2.f / 3.f);
            vg[r][g][0] = vgx; vg[r][g][1] = vgy;
            float* vp = vgrid_g + ((b * GROUPS + g) * NQ + n0 + r) * 2;
            vp[0] = vgx; vp[1] = vgy;
        }
    }
    __syncthreads();
    #pragma unroll
    for (int rep = 0; rep < 4; ++rep) {
        int idx = rep * 256 + t;
        int r = idx >> 8, c = idx & 255, g = c >> 5;
        float x = (vg[r][g][0] + 1.f) * 2.f - 0.5f;
        float y = (vg[r][g][1] + 1.f) * 2.f - 0.5f;
        float x0f = floorf(x), y0f = floorf(y);
        float wx = x - x0f, wy = y - y0f;
        int x0 = (int)x0f, y0 = (int)y0f;
        const float* img = rgb + (b * DIMC + c) * HWT;
        float v00 = samp4(img, y0, x0), v01 = samp4(img, y0, x0 + 1);
        float v10 = samp4(img, y0 + 1, x0), v11 = samp4(img, y0 + 1, x0 + 1);
        kvs[r][c] = v00 * (1.f - wx) * (1.f - wy) + v01 * wx * (1.f - wy)
                  + v10 * (1.f - wx) * wy + v11 * wx * wy;
    }
    __syncthreads();
    // grouped k/v convs; K transposed [bg][d][n], V row-major [b][n][inner]
    #pragma unroll
    for (int rep = 0; rep < 2; ++rep) {
        int ch = rep * 256 + t;
        int g = ch >> 6;
        float ak[4] = {0.f, 0.f, 0.f, 0.f};
        float av[4] = {0.f, 0.f, 0.f, 0.f};
        #pragma unroll
        for (int ci = 0; ci < 32; ++ci) {
            float wk = kwT[ci * INNER + ch];
            float wv = vwT[ci * INNER + ch];
            #pragma unroll
            for (int r = 0; r < 4; ++r) {
                float x = kvs[r][g * 32 + ci];
                ak[r] = fmaf(wk, x, ak[r]);
                av[r] = fmaf(wv, x, av[r]);
            }
        }
        int hh = ch >> 6, dh = ch & 63;
        float4 kk; kk.x = ak[0]; kk.y = ak[1]; kk.z = ak[2]; kk.w = ak[3];
        *(float4*)(kTt + ((b * HEADS + hh) * DH + dh) * NQ + n0) = kk;
        #pragma unroll
        for (int r = 0; r < 4; ++r)
            vT[(b * NQ + n0 + r) * INNER + ch] = av[r];
    }
}

// ---------------- K3a: CPB bias via fp16 MFMA, amortized prologue ----------------
// grid 1024: blockIdx = (bg*16 + jt)*2 + itc; block: 16 j x 128 i (8 it-tiles).
// Weight prologue paid once per 16 body iterations (was 4 at grid 4096).
// mfma_f32_16x16x32_f16(A=w1, B=h0): C col (lane&15) = i, C row (4*lgp+reg)
// = c2. Two independent j-chains per body; acc tiles in 2 nt-passes.
__global__ __launch_bounds__(256) void k3a_bias(
        const float* __restrict__ pose_init, const float* __restrict__ vgrid_g,
        const float* __restrict__ w0, const float* __restrict__ b0,
        const float* __restrict__ b1, const float* __restrict__ w1,
        const float* __restrict__ w2, const float* __restrict__ b2,
        ushort_t* __restrict__ bias) {
    int bg = blockIdx.x >> 5;
    int jt = (blockIdx.x >> 1) & 15;
    int itc = blockIdx.x & 1;
    int b = bg >> 3;
    int tid = threadIdx.x;
    int wv = tid >> 6, lane = tid & 63;
    int lgp = lane >> 4, lr = lane & 15;

    __shared__ float gx_s[128], gy_s[128];
    __shared__ float2 b1w2_s[64];
    __shared__ float2 vg_s[16];
    __shared__ unsigned b0_lds[4][8];   // [lgp][kc*4+e2] packed fp16 pairs
    // phase A: gx/gy (all 256 threads)
    if (tid < 128) {
        gx_s[tid] = 2.f * pose_init[(b * 2 + 0) * NQ + itc * 128 + tid] - 1.f;
    } else {
        gy_s[tid - 128] = 2.f * pose_init[(b * 2 + 1) * NQ + itc * 128 + (tid - 128)] - 1.f;
    }
    // phase B: small tables (disjoint arrays, same pass)
    if (tid < 64) {
        float2 bw; bw.x = b1[tid]; bw.y = w2[tid];
        b1w2_s[tid] = bw;
    } else if (tid < 80) {
        int j = jt * 16 + (tid - 64);
        vg_s[tid - 64] = ((const float2*)vgrid_g)[bg * NQ + j];
    } else if (tid < 112) {
        int idx = tid - 80;
        int lg2 = idx >> 3, rem = idx & 7, kc = rem >> 2, e2 = rem & 3;
        int c = kc * 32 + lg2 * 8 + 2 * e2;
        b0_lds[lg2][kc * 4 + e2] = pkrtz(b0[c], b0[c + 1]);
    }
    __syncthreads();

    // layer-0 weights as packed fp16 pairs (k = kc*32 + lgp*8 + 2*e2 {+1})
    unsigned w0a_pk[2][4], w0b_pk[2][4];
    #pragma unroll
    for (int kc = 0; kc < 2; ++kc)
        #pragma unroll
        for (int e2 = 0; e2 < 4; ++e2) {
            int c = kc * 32 + lgp * 8 + 2 * e2;
            w0a_pk[kc][e2] = pkrtz(w0[2 * c],     w0[2 * (c + 1)]);
            w0b_pk[kc][e2] = pkrtz(w0[2 * c + 1], w0[2 * (c + 1) + 1]);
        }
    // w1 as fp16 A-fragment: row c2 = nt*16 + lr, k = kc*32 + lgp*8 + e
    half8v w1f[2][4];
    #pragma unroll
    for (int nt = 0; nt < 4; ++nt) {
        int c2 = nt * 16 + lr;
        #pragma unroll
        for (int kc = 0; kc < 2; ++kc) {
            union { half8v v; unsigned u[4]; } tmp;
            #pragma unroll
            for (int e2 = 0; e2 < 4; ++e2) {
                int kk = kc * 32 + lgp * 8 + 2 * e2;
                tmp.u[e2] = pkrtz(w1[c2 * 64 + kk], w1[c2 * 64 + kk + 1]);
            }
            w1f[kc][nt] = tmp.v;
        }
    }
    float b2v = b2[0];
    ushort_t* brow_base = bias + bg * NQ * NQ;

    #pragma unroll 1
    for (int it2 = 0; it2 < 8; ++it2) {
        int it = itc * 8 + it2;
        float gxi = gx_s[it2 * 16 + lr], gyi = gy_s[it2 * 16 + lr];
        #pragma unroll 1
        for (int jp = 0; jp < 2; ++jp) {
            int jlA = wv * 4 + jp * 2;
            int jA = jt * 16 + jlA;
            float2 vgA = vg_s[jlA], vgB = vg_s[jlA + 1];
            float pxA = gxi - vgA.x, pyA = gyi - vgA.y;
            float pxB = gxi - vgB.x, pyB = gyi - vgB.y;
            float uA = copysignf(__logf(1.f + fabsf(pxA)), pxA);
            float vA = copysignf(__logf(1.f + fabsf(pyA)), pyA);
            float uB = copysignf(__logf(1.f + fabsf(pxB)), pxB);
            float vB = copysignf(__logf(1.f + fabsf(pyB)), pyB);
            unsigned uuA = pkrtz(uA, uA), vvA = pkrtz(vA, vA);
            unsigned uuB = pkrtz(uB, uB), vvB = pkrtz(vB, vB);
            // layer-0 for both j (independent chains)
            union { half8v v; unsigned u[4]; } hA0, hA1, hB0, hB1;
            #pragma unroll
            for (int e2 = 0; e2 < 4; ++e2) {
                hA0.u[e2] = pk_max0_f16(pk_fma_f16(w0a_pk[0][e2], uuA,
                              pk_fma_f16(w0b_pk[0][e2], vvA, b0_lds[lgp][e2])));
                hB0.u[e2] = pk_max0_f16(pk_fma_f16(w0a_pk[0][e2], uuB,
                              pk_fma_f16(w0b_pk[0][e2], vvB, b0_lds[lgp][e2])));
                hA1.u[e2] = pk_max0_f16(pk_fma_f16(w0a_pk[1][e2], uuA,
                              pk_fma_f16(w0b_pk[1][e2], vvA, b0_lds[lgp][4 + e2])));
                hB1.u[e2] = pk_max0_f16(pk_fma_f16(w0a_pk[1][e2], uuB,
                              pk_fma_f16(w0b_pk[1][e2], vvB, b0_lds[lgp][4 + e2])));
            }
            float sA = 0.f, sB = 0.f;
            #pragma unroll
            for (int ntp = 0; ntp < 2; ++ntp) {
                int n0t = 2 * ntp, n1t = 2 * ntp + 1;
                f32x4 aA0 = {0.f, 0.f, 0.f, 0.f};
                f32x4 aA1 = {0.f, 0.f, 0.f, 0.f};
                f32x4 aB0 = {0.f, 0.f, 0.f, 0.f};
                f32x4 aB1 = {0.f, 0.f, 0.f, 0.f};
                aA0 = __builtin_amdgcn_mfma_f32_16x16x32_f16(w1f[0][n0t], hA0.v, aA0, 0, 0, 0);
                aB0 = __builtin_amdgcn_mfma_f32_16x16x32_f16(w1f[0][n0t], hB0.v, aB0, 0, 0, 0);
                aA0 = __builtin_amdgcn_mfma_f32_16x16x32_f16(w1f[1][n0t], hA1.v, aA0, 0, 0, 0);
                aB0 = __builtin_amdgcn_mfma_f32_16x16x32_f16(w1f[1][n0t], hB1.v, aB0, 0, 0, 0);
                aA1 = __builtin_amdgcn_mfma_f32_16x16x32_f16(w1f[0][n1t], hA0.v, aA1, 0, 0, 0);
                aB1 = __builtin_amdgcn_mfma_f32_16x16x32_f16(w1f[0][n1t], hB0.v, aB1, 0, 0, 0);
                aA1 = __builtin_amdgcn_mfma_f32_16x16x32_f16(w1f[1][n1t], hA1.v, aA1, 0, 0, 0);
                aB1 = __builtin_amdgcn_mfma_f32_16x16x32_f16(w1f[1][n1t], hB1.v, aB1, 0, 0, 0);
                #pragma unroll
                for (int r = 0; r < 4; ++r) {
                    float2 bw0 = b1w2_s[n0t * 16 + 4 * lgp + r];
                    float2 bw1 = b1w2_s[n1t * 16 + 4 * lgp + r];
                    sA += fmaxf(aA0[r] + bw0.x, 0.f) * bw0.y;
                    sB += fmaxf(aB0[r] + bw0.x, 0.f) * bw0.y;
                    sA += fmaxf(aA1[r] + bw1.x, 0.f) * bw1.y;
                    sB += fmaxf(aB1[r] + bw1.x, 0.f) * bw1.y;
                }
            }
            sA += __shfl_xor(sA, 16, 64);
            sB += __shfl_xor(sB, 16, 64);
            sA += __shfl_xor(sA, 32, 64);
            sB += __shfl_xor(sB, 32, 64);
            if (lane < 16) {
                ushort_t* row = brow_base + (it * 16 + lr) * NQ + jA;
                row[0] = (ushort_t)f2bf(sA + b2v);
                row[1] = (ushort_t)f2bf(sB + b2v);
            }
        }
    }
}

// ---------------- K3b: sim + bias + softmax + attn@V ----------------
__global__ __launch_bounds__(256) void k3b_attn(
        const float* __restrict__ qT, const float* __restrict__ kTt,
        const float* __restrict__ vT, const ushort_t* __restrict__ bias,
        float* __restrict__ aoT) {
    int bg = blockIdx.x >> 5;
    int itile = blockIdx.x & 31;
    int b = bg >> 3, h = bg & 7;
    int i0 = itile * 8;
    int tid = threadIdx.x;

    __shared__ __align__(16) float q_s[8][64];
    __shared__ __align__(16) float attn_s[8][NQ];
    __shared__ float ssum_s[8];

    for (int idx = tid; idx < 8 * 64; idx += 256) {
        int i = idx >> 6, d = idx & 63;
        q_s[i][d] = qT[(b * NQ + i0 + i) * INNER + h * 64 + d] * 0.125f;
    }
    __syncthreads();

    {
        int jq = tid & 63, ih = tid >> 6;
        const float4* kb4 = (const float4*)(kTt + bg * DH * NQ) + jq;
        float4 s0 = {0.f, 0.f, 0.f, 0.f};
        float4 s1 = {0.f, 0.f, 0.f, 0.f};
        #pragma unroll 4
        for (int d = 0; d < 64; ++d) {
            float4 kv = kb4[d * 64];
            float q0 = q_s[ih][d], q1 = q_s[ih + 4][d];
            s0.x = fmaf(q0, kv.x, s0.x); s0.y = fmaf(q0, kv.y, s0.y);
            s0.z = fmaf(q0, kv.z, s0.z); s0.w = fmaf(q0, kv.w, s0.w);
            s1.x = fmaf(q1, kv.x, s1.x); s1.y = fmaf(q1, kv.y, s1.y);
            s1.z = fmaf(q1, kv.z, s1.z); s1.w = fmaf(q1, kv.w, s1.w);
        }
        uint2 bb0 = *(const uint2*)(bias + (bg * NQ + i0 + ih) * NQ + jq * 4);
        uint2 bb1 = *(const uint2*)(bias + (bg * NQ + i0 + ih + 4) * NQ + jq * 4);
        s0.x += bf2f(bb0.x & 0xffffu); s0.y += bf2f(bb0.x >> 16);
        s0.z += bf2f(bb0.y & 0xffffu); s0.w += bf2f(bb0.y >> 16);
        s1.x += bf2f(bb1.x & 0xffffu); s1.y += bf2f(bb1.x >> 16);
        s1.z += bf2f(bb1.y & 0xffffu); s1.w += bf2f(bb1.y >> 16);
        *(float4*)&attn_s[ih][jq * 4] = s0;
        *(float4*)&attn_s[ih + 4][jq * 4] = s1;
    }
    __syncthreads();
    {
        int il = tid >> 5, lane = tid & 31;
        float m = -1e30f;
        for (int jj = 0; jj < 8; ++jj) m = fmaxf(m, attn_s[il][jj * 32 + lane]);
        #pragma unroll
        for (int o = 16; o > 0; o >>= 1) m = fmaxf(m, __shfl_xor(m, o, 32));
        float s = 0.f;
        for (int jj = 0; jj < 8; ++jj) {
            int j = jj * 32 + lane;
            float e = __expf(attn_s[il][j] - m);
            attn_s[il][j] = e;
            s += e;
        }
        #pragma unroll
        for (int o = 16; o > 0; o >>= 1) s += __shfl_xor(s, o, 32);
        if (lane == 0) ssum_s[il] = s;
    }
    __syncthreads();
    {
        int lane = tid & 31, il = tid >> 5;
        const float2* vp = (const float2*)(vT + b * NQ * INNER + h * 64) + lane;
        float a0 = 0.f, a1 = 0.f, c0 = 0.f, c1 = 0.f;
        #pragma unroll 4
        for (int j = 0; j < NQ; j += 2) {
            float w0 = attn_s[il][j], w1 = attn_s[il][j + 1];
            float2 v0 = vp[j * (INNER / 2)];
            float2 v1 = vp[(j + 1) * (INNER / 2)];
            a0 = fmaf(w0, v0.x, a0); a1 = fmaf(w0, v0.y, a1);
            c0 = fmaf(w1, v1.x, c0); c1 = fmaf(w1, v1.y, c1);
        }
        float r = 1.f / ssum_s[il];
        float2 res; res.x = (a0 + c0) * r; res.y = (a1 + c1) * r;
        *(float2*)(aoT + (b * NQ + i0 + il) * INNER + h * 64 + lane * 2) = res;
    }
}

// ---------------- K4: final projection 512 -> 256 (coalesced owT) ----------------
__global__ __launch_bounds__(256) void k4_proj(const float* __restrict__ aoT,
        const float* __restrict__ owT, const float* __restrict__ out_b,
        float* __restrict__ out) {
    int b = blockIdx.x >> 6;
    int n0 = (blockIdx.x & 63) * 4;
    int t = threadIdx.x;
    __shared__ __align__(16) float xl[4][INNER];
    for (int idx = t; idx < 4 * INNER; idx += 256) {
        xl[idx >> 9][idx & 511] = aoT[(b * NQ + n0) * INNER + idx];
    }
    __syncthreads();
    float bo = out_b[t];
    float a0 = bo, a1 = bo, a2 = bo, a3 = bo;
    #pragma unroll 2
    for (int c4 = 0; c4 < 128; ++c4) {
        int c = c4 * 4;
        float w0 = owT[(c + 0) * DIMC + t];
        float w1 = owT[(c + 1) * DIMC + t];
        float w2 = owT[(c + 2) * DIMC + t];
        float w3 = owT[(c + 3) * DIMC + t];
        float4 x0 = *(const float4*)&xl[0][c];
        float4 x1 = *(const float4*)&xl[1][c];
        float4 x2 = *(const float4*)&xl[2][c];
        float4 x3 = *(const float4*)&xl[3][c];
        a0 = fmaf(w0, x0.x, a0); a0 = fmaf(w1, x0.y, a0); a0 = fmaf(w2, x0.z, a0); a0 = fmaf(w3, x0.w, a0);
        a1 = fmaf(w0, x1.x, a1); a1 = fmaf(w1, x1.y, a1); a1 = fmaf(w2, x1.z, a1); a1 = fmaf(w3, x1.w, a1);
        a2 = fmaf(w0, x2.x, a2); a2 = fmaf(w1, x2.y, a2); a2 = fmaf(w2, x2.z, a2); a2 = fmaf(w3, x2.w, a2);
        a3 = fmaf(w0, x3.x, a3); a3 = fmaf(w1, x3.y, a3); a3 = fmaf(w2, x3.z, a3); a3 = fmaf(w3, x3.w, a3);
    }
    float4 res; res.x = a0; res.y = a1; res.z = a2; res.w = a3;
    *(float4*)(out + (b * DIMC + t) * NQ + n0) = res;
}

extern "C" void kernel_launch(void* const* d_in, const int* in_sizes, int n_in,
                              void* d_out, int out_size, void* d_ws, size_t ws_size,
                              hipStream_t stream) {
    const float* pose_feat = (const float*)d_in[0];
    const float* rgb       = (const float*)d_in[1];
    const float* pose_init = (const float*)d_in[2];
    const float* mha_in_w  = (const float*)d_in[3];
    const float* mha_in_b  = (const float*)d_in[4];
    const float* mha_out_w = (const float*)d_in[5];
    const float* mha_out_b = (const float*)d_in[6];
    const float* pe_gauss  = (const float*)d_in[7];
    const float* off_w1    = (const float*)d_in[8];
    const float* off_b1    = (const float*)d_in[9];
    const float* off_w2    = (const float*)d_in[10];
    const float* cpb_w0    = (const float*)d_in[11];
    const float* cpb_b0    = (const float*)d_in[12];
    const float* cpb_w1    = (const float*)d_in[13];
    const float* cpb_b1    = (const float*)d_in[14];
    const float* cpb_w2    = (const float*)d_in[15];
    const float* cpb_b2    = (const float*)d_in[16];
    const float* q_w       = (const float*)d_in[17];
    const float* k_w       = (const float*)d_in[18];
    const float* v_w       = (const float*)d_in[19];
    const float* out_w     = (const float*)d_in[20];
    const float* out_b     = (const float*)d_in[21];

    float* ws    = (float*)d_ws;
    float* kx    = ws;                     // 16384
    float* vx    = kx + 16384;             // 16384
    float* qT    = vx + 16384;             // 524288
    float* kTt   = qT + 524288;            // 524288
    float* vT    = kTt + 524288;           // 524288
    float* vgrid = vT + 524288;            // 16384
    float* aoT   = vgrid + 16384;          // 524288
    float* WqT   = aoT + 524288;           // 65536
    float* mowT  = WqT + 65536;            // 65536
    float* owT   = mowT + 65536;           // 131072
    float* qwT   = owT + 131072;           // 16384
    float* kwT   = qwT + 16384;            // 16384
    float* vwT   = kwT + 16384;            // 16384
    ushort_t* bias = (ushort_t*)(vwT + 16384);   // 32*256*256 bf16 = 4 MB
    float* out   = (float*)d_out;

    k0_tr<<<1216, 256, 0, stream>>>(mha_in_w, mha_out_w, out_w, q_w, k_w, v_w,
        WqT, mowT, owT, qwT, kwT, vwT);
    k1_kv<<<64, 256, 0, stream>>>(rgb, mha_in_w, mha_in_b, kx, vx);
    k2_qkv<<<256, 256, 0, stream>>>(pose_feat, rgb, pose_init, mha_in_b,
        WqT, mowT, mha_out_b, pe_gauss, off_w1, off_b1, off_w2, qwT, kwT, vwT,
        kx, vx, qT, kTt, vT, vgrid);
    k3a_bias<<<1024, 256, 0, stream>>>(pose_init, vgrid,
        cpb_w0, cpb_b0, cpb_b1, cpb_w1, cpb_w2, cpb_b2, bias);
    k3b_attn<<<1024, 256, 0, stream>>>(qT, kTt, vT, bias, aoT);
    k4_proj<<<256, 256, 0, stream>>>(aoT, owT, out_b, out);
}

// Round 17
// 148.199 us; speedup vs baseline: 1.9035x; 1.1314x over previous
//
#include <hip/hip_runtime.h>
#include <hip/hip_bf16.h>
#include <math.h>

// DeformableAttention2D — round 17: k3b PV via LDS-staged V chunks (4 x
// 64j x 64d, 16KB): converts 256 strided-2KB L2 loads/thread into 16 dense
// float4 loads + LDS reads. sim unroll 4->8. k3a/k2 unchanged from r16.
// Sizes (fixed): B=4, N=256, DIM=256, HEADS=8, GROUPS=8, INNER=512, DH=64,
// cross-attn head dim 32, rgb 4x4 (16 tokens), CPB MLP 2->64->64->1.

#define DIMC 256
#define NQ 256
#define HEADS 8
#define GROUPS 8
#define INNER 512
#define DH 64
#define HDX 32
#define HWT 16

typedef __attribute__((ext_vector_type(8))) short short8v;
typedef __attribute__((ext_vector_type(8))) _Float16 half8v;
typedef __attribute__((ext_vector_type(4))) float f32x4;
typedef unsigned short ushort_t;

__device__ __forceinline__ float gelu_exact(float x) {
    return 0.5f * x * (1.f + erff(x * 0.70710678118654752f));
}
__device__ __forceinline__ short f2bf(float x) {
    union { float f; unsigned u; } c; c.f = x;
    unsigned r = c.u + 0x7fffu + ((c.u >> 16) & 1u);
    return (short)(r >> 16);
}
__device__ __forceinline__ float bf2f(unsigned hbits) {
    union { unsigned u; float f; } c; c.u = hbits << 16;
    return c.f;
}
__device__ __forceinline__ unsigned pkrtz(float a, float b) {
    auto h = __builtin_amdgcn_cvt_pkrtz(a, b);
    union { decltype(h) h2; unsigned u; } c; c.h2 = h; return c.u;
}
__device__ __forceinline__ unsigned pk_fma_f16(unsigned a, unsigned b, unsigned c) {
    unsigned d;
    asm("v_pk_fma_f16 %0, %1, %2, %3" : "=v"(d) : "v"(a), "v"(b), "v"(c));
    return d;
}
__device__ __forceinline__ unsigned pk_max0_f16(unsigned a) {
    unsigned d;
    asm("v_pk_max_f16 %0, %1, %2" : "=v"(d) : "v"(a), "v"(0u));
    return d;
}
__device__ __forceinline__ float samp4(const float* __restrict__ img, int yi, int xi) {
    bool valid = (xi >= 0) && (xi < 4) && (yi >= 0) && (yi < 4);
    int idx = min(max(yi, 0), 3) * 4 + min(max(xi, 0), 3);
    return valid ? img[idx] : 0.f;
}

// ---------------- K0: weight transposes ----------------
__global__ __launch_bounds__(256) void k0_tr(
        const float* __restrict__ in_w, const float* __restrict__ mow,
        const float* __restrict__ out_w, const float* __restrict__ q_w,
        const float* __restrict__ k_w, const float* __restrict__ v_w,
        float* __restrict__ WqT, float* __restrict__ mowT,
        float* __restrict__ owT, float* __restrict__ qwT,
        float* __restrict__ kwT, float* __restrict__ vwT) {
    int idx = blockIdx.x * 256 + threadIdx.x;
    if (idx < 65536) {
        int d = idx >> 8, o = idx & 255;
        WqT[idx] = in_w[o * 256 + d];
    } else if (idx < 131072) {
        int k = idx - 65536; int d = k >> 8, o = k & 255;
        mowT[k] = mow[o * 256 + d];
    } else if (idx < 262144) {
        int k = idx - 131072; int c = k >> 8, o = k & 255;
        owT[k] = out_w[o * 512 + c];
    } else if (idx < 278528) {
        int k = idx - 262144; int ci = k >> 9, ch = k & 511;
        qwT[k] = q_w[ch * 32 + ci];
    } else if (idx < 294912) {
        int k = idx - 278528; int ci = k >> 9, ch = k & 511;
        kwT[k] = k_w[ch * 32 + ci];
    } else if (idx < 311296) {
        int k = idx - 294912; int ci = k >> 9, ch = k & 511;
        vwT[k] = v_w[ch * 32 + ci];
    }
}

// ---------------- K1: kx, vx  [b,16,256] ----------------
__global__ __launch_bounds__(256) void k1_kv(const float* __restrict__ rgb,
        const float* __restrict__ in_w, const float* __restrict__ in_b,
        float* __restrict__ kx, float* __restrict__ vx) {
    int b = blockIdx.x >> 4;
    int tt = blockIdx.x & 15;
    int c = threadIdx.x;
    __shared__ __align__(16) float kvin[DIMC];
    float ang = (float)tt * powf(10000.f, -(float)(c >> 1) * (1.f / 128.f));
    float sv = (c & 1) ? cosf(ang) : sinf(ang);
    kvin[c] = rgb[(b * DIMC + c) * HWT + tt] + sv;
    __syncthreads();
    const float4* x4 = (const float4*)kvin;
    const float4* wk4 = (const float4*)(in_w + (DIMC + c) * DIMC);
    const float4* wv4 = (const float4*)(in_w + (2 * DIMC + c) * DIMC);
    float ak0 = in_b[DIMC + c], ak1 = 0.f, av0 = in_b[2 * DIMC + c], av1 = 0.f;
    #pragma unroll 4
    for (int d4 = 0; d4 < 64; ++d4) {
        float4 x = x4[d4], wk = wk4[d4], wv = wv4[d4];
        ak0 = fmaf(wk.x, x.x, ak0); ak1 = fmaf(wk.y, x.y, ak1);
        ak0 = fmaf(wk.z, x.z, ak0); ak1 = fmaf(wk.w, x.w, ak1);
        av0 = fmaf(wv.x, x.x, av0); av1 = fmaf(wv.y, x.y, av1);
        av0 = fmaf(wv.z, x.z, av0); av1 = fmaf(wv.w, x.w, av1);
    }
    kx[(b * HWT + tt) * DIMC + c] = ak0 + ak1;
    vx[(b * HWT + tt) * DIMC + c] = av0 + av1;
}

// ---------------- K2: 4 rows per block ----------------
__global__ __launch_bounds__(256) void k2_qkv(
        const float* __restrict__ pose_feat, const float* __restrict__ rgb,
        const float* __restrict__ pose_init, const float* __restrict__ in_b,
        const float* __restrict__ WqT, const float* __restrict__ mowT,
        const float* __restrict__ mob, const float* __restrict__ pe_gauss,
        const float* __restrict__ off_w1, const float* __restrict__ off_b1,
        const float* __restrict__ off_w2,
        const float* __restrict__ qwT, const float* __restrict__ kwT,
        const float* __restrict__ vwT,
        const float* __restrict__ kx, const float* __restrict__ vx,
        float* __restrict__ qT, float* __restrict__ kTt, float* __restrict__ vT,
        float* __restrict__ vgrid_g) {
    int b = blockIdx.x >> 6;
    int n0 = (blockIdx.x & 63) * 4;
    int t = threadIdx.x;
    __shared__ __align__(16) float xs[4][DIMC];
    __shared__ __align__(16) float qxs[4][DIMC];
    __shared__ __align__(16) float ctx[4][DIMC];
    __shared__ __align__(16) float x2[4][DIMC];
    __shared__ float lg[4][128], psm[4][128];
    __shared__ float qls[4][INNER];
    __shared__ float kvs[4][DIMC];
    __shared__ float vg[4][GROUPS][2];
    __shared__ float g01[4][2];

    if (t < 8) {
        int r = t >> 1, comp = t & 1;
        g01[r][comp] = 2.f * pose_init[(b * 2 + comp) * NQ + n0 + r] - 1.f;
    }
    float4 pf4 = *(const float4*)(pose_feat + (b * DIMC + t) * NQ + n0);
    float pfv[4] = {pf4.x, pf4.y, pf4.z, pf4.w};
    __syncthreads();
    {
        int j = t & 127;
        float pj0 = pe_gauss[j], pj1 = pe_gauss[128 + j];
        #pragma unroll
        for (int r = 0; r < 4; ++r) {
            float cc = (g01[r][0] * pj0 + g01[r][1] * pj1) * 6.28318530717958648f;
            float sc = (t < 128) ? sinf(cc) : cosf(cc);
            xs[r][t] = pfv[r] + sc;
        }
    }
    __syncthreads();
    {
        float bq = in_b[t];
        float a0 = bq, a1 = bq, a2 = bq, a3 = bq;
        #pragma unroll 2
        for (int d4 = 0; d4 < 64; ++d4) {
            int d = d4 * 4;
            float w0 = WqT[(d + 0) * DIMC + t];
            float w1 = WqT[(d + 1) * DIMC + t];
            float w2 = WqT[(d + 2) * DIMC + t];
            float w3 = WqT[(d + 3) * DIMC + t];
            float4 x0 = *(const float4*)&xs[0][d];
            float4 x1 = *(const float4*)&xs[1][d];
            float4 x2_ = *(const float4*)&xs[2][d];
            float4 x3 = *(const float4*)&xs[3][d];
            a0 = fmaf(w0, x0.x, a0); a0 = fmaf(w1, x0.y, a0); a0 = fmaf(w2, x0.z, a0); a0 = fmaf(w3, x0.w, a0);
            a1 = fmaf(w0, x1.x, a1); a1 = fmaf(w1, x1.y, a1); a1 = fmaf(w2, x1.z, a1); a1 = fmaf(w3, x1.w, a1);
            a2 = fmaf(w0, x2_.x, a2); a2 = fmaf(w1, x2_.y, a2); a2 = fmaf(w2, x2_.z, a2); a2 = fmaf(w3, x2_.w, a2);
            a3 = fmaf(w0, x3.x, a3); a3 = fmaf(w1, x3.y, a3); a3 = fmaf(w2, x3.z, a3); a3 = fmaf(w3, x3.w, a3);
        }
        qxs[0][t] = a0; qxs[1][t] = a1; qxs[2][t] = a2; qxs[3][t] = a3;
    }
    __syncthreads();
    #pragma unroll
    for (int rep = 0; rep < 2; ++rep) {
        int idx = rep * 256 + t;
        int r = idx >> 7, hh = (idx >> 4) & 7, tt = idx & 15;
        const float4* kp = (const float4*)(kx + (b * HWT + tt) * DIMC + hh * HDX);
        const float4* qp = (const float4*)(&qxs[r][hh * HDX]);
        float a = 0.f;
        #pragma unroll
        for (int d4 = 0; d4 < 8; ++d4) {
            float4 k4 = kp[d4], q4 = qp[d4];
            a = fmaf(q4.x, k4.x, a); a = fmaf(q4.y, k4.y, a);
            a = fmaf(q4.z, k4.z, a); a = fmaf(q4.w, k4.w, a);
        }
        lg[r][hh * 16 + tt] = a * 0.17677669529663689f;
    }
    __syncthreads();
    if (t < 32) {
        int r = t >> 3, hh = t & 7;
        float m = -1e30f;
        for (int tt = 0; tt < 16; ++tt) m = fmaxf(m, lg[r][hh * 16 + tt]);
        float s = 0.f;
        for (int tt = 0; tt < 16; ++tt) {
            float e = __expf(lg[r][hh * 16 + tt] - m);
            psm[r][hh * 16 + tt] = e; s += e;
        }
        float rr = 1.f / s;
        for (int tt = 0; tt < 16; ++tt) psm[r][hh * 16 + tt] *= rr;
    }
    __syncthreads();
    {
        int hh = t >> 5;
        const float* vp = vx + b * HWT * DIMC + t;
        float a0 = 0.f, a1 = 0.f, a2 = 0.f, a3 = 0.f;
        #pragma unroll
        for (int tt = 0; tt < 16; ++tt) {
            float vv = vp[tt * DIMC];
            a0 = fmaf(psm[0][hh * 16 + tt], vv, a0);
            a1 = fmaf(psm[1][hh * 16 + tt], vv, a1);
            a2 = fmaf(psm[2][hh * 16 + tt], vv, a2);
            a3 = fmaf(psm[3][hh * 16 + tt], vv, a3);
        }
        ctx[0][t] = a0; ctx[1][t] = a1; ctx[2][t] = a2; ctx[3][t] = a3;
    }
    __syncthreads();
    {
        float bm = mob[t];
        float a0 = bm, a1 = bm, a2 = bm, a3 = bm;
        #pragma unroll 2
        for (int d4 = 0; d4 < 64; ++d4) {
            int d = d4 * 4;
            float w0 = mowT[(d + 0) * DIMC + t];
            float w1 = mowT[(d + 1) * DIMC + t];
            float w2 = mowT[(d + 2) * DIMC + t];
            float w3 = mowT[(d + 3) * DIMC + t];
            float4 c0 = *(const float4*)&ctx[0][d];
            float4 c1 = *(const float4*)&ctx[1][d];
            float4 c2 = *(const float4*)&ctx[2][d];
            float4 c3 = *(const float4*)&ctx[3][d];
            a0 = fmaf(w0, c0.x, a0); a0 = fmaf(w1, c0.y, a0); a0 = fmaf(w2, c0.z, a0); a0 = fmaf(w3, c0.w, a0);
            a1 = fmaf(w0, c1.x, a1); a1 = fmaf(w1, c1.y, a1); a1 = fmaf(w2, c1.z, a1); a1 = fmaf(w3, c1.w, a1);
            a2 = fmaf(w0, c2.x, a2); a2 = fmaf(w1, c2.y, a2); a2 = fmaf(w2, c2.z, a2); a2 = fmaf(w3, c2.w, a2);
            a3 = fmaf(w0, c3.x, a3); a3 = fmaf(w1, c3.y, a3); a3 = fmaf(w2, c3.z, a3); a3 = fmaf(w3, c3.w, a3);
        }
        x2[0][t] = pfv[0] + a0; x2[1][t] = pfv[1] + a1;
        x2[2][t] = pfv[2] + a2; x2[3][t] = pfv[3] + a3;
    }
    __syncthreads();
    #pragma unroll
    for (int rep = 0; rep < 2; ++rep) {
        int ch = rep * 256 + t;
        int g = ch >> 6;
        float aq[4] = {0.f, 0.f, 0.f, 0.f};
        #pragma unroll
        for (int ci = 0; ci < 32; ++ci) {
            float w = qwT[ci * INNER + ch];
            aq[0] = fmaf(w, x2[0][g * 32 + ci], aq[0]);
            aq[1] = fmaf(w, x2[1][g * 32 + ci], aq[1]);
            aq[2] = fmaf(w, x2[2][g * 32 + ci], aq[2]);
            aq[3] = fmaf(w, x2[3][g * 32 + ci], aq[3]);
        }
        #pragma unroll
        for (int r = 0; r < 4; ++r) {
            qls[r][ch] = aq[r];
            qT[(b * NQ + n0 + r) * INNER + ch] = aq[r];
        }
    }
    __syncthreads();
    {
        int pr = t >> 3, l = t & 7;
        int r = pr >> 3, g = pr & 7;
        float s0 = 0.f, s1 = 0.f;
        #pragma unroll
        for (int e = 0; e < 8; ++e) {
            int jj = l * 8 + e;
            float ev = gelu_exact(fmaf(qls[r][g * 64 + jj], off_w1[jj], off_b1[jj]));
            s0 = fmaf(ev, off_w2[jj], s0);
            s1 = fmaf(ev, off_w2[64 + jj], s1);
        }
        #pragma unroll
        for (int o = 4; o > 0; o >>= 1) {
            s0 += __shfl_xor(s0, o, 64);
            s1 += __shfl_xor(s1, o, 64);
        }
        if (l == 0) {
            float vgx = g01[r][0] + tanhf(s0) * (2.f / 3.f);
            float vgy = g01[r][1] + tanhf(s1) * (2.f / 3.f);
            vg[r][g][0] = vgx; vg[r][g][1] = vgy;
            float* vp = vgrid_g + ((b * GROUPS + g) * NQ + n0 + r) * 2;
            vp[0] = vgx; vp[1] = vgy;
        }
    }
    __syncthreads();
    #pragma unroll
    for (int rep = 0; rep < 4; ++rep) {
        int idx = rep * 256 + t;
        int r = idx >> 8, c = idx & 255, g = c >> 5;
        float x = (vg[r][g][0] + 1.f) * 2.f - 0.5f;
        float y = (vg[r][g][1] + 1.f) * 2.f - 0.5f;
        float x0f = floorf(x), y0f = floorf(y);
        float wx = x - x0f, wy = y - y0f;
        int x0 = (int)x0f, y0 = (int)y0f;
        const float* img = rgb + (b * DIMC + c) * HWT;
        float v00 = samp4(img, y0, x0), v01 = samp4(img, y0, x0 + 1);
        float v10 = samp4(img, y0 + 1, x0), v11 = samp4(img, y0 + 1, x0 + 1);
        kvs[r][c] = v00 * (1.f - wx) * (1.f - wy) + v01 * wx * (1.f - wy)
                  + v10 * (1.f - wx) * wy + v11 * wx * wy;
    }
    __syncthreads();
    // grouped k/v convs; K transposed [bg][d][n], V row-major [b][n][inner]
    #pragma unroll
    for (int rep = 0; rep < 2; ++rep) {
        int ch = rep * 256 + t;
        int g = ch >> 6;
        float ak[4] = {0.f, 0.f, 0.f, 0.f};
        float av[4] = {0.f, 0.f, 0.f, 0.f};
        #pragma unroll
        for (int ci = 0; ci < 32; ++ci) {
            float wk = kwT[ci * INNER + ch];
            float wv = vwT[ci * INNER + ch];
            #pragma unroll
            for (int r = 0; r < 4; ++r) {
                float x = kvs[r][g * 32 + ci];
                ak[r] = fmaf(wk, x, ak[r]);
                av[r] = fmaf(wv, x, av[r]);
            }
        }
        int hh = ch >> 6, dh = ch & 63;
        float4 kk; kk.x = ak[0]; kk.y = ak[1]; kk.z = ak[2]; kk.w = ak[3];
        *(float4*)(kTt + ((b * HEADS + hh) * DH + dh) * NQ + n0) = kk;
        #pragma unroll
        for (int r = 0; r < 4; ++r)
            vT[(b * NQ + n0 + r) * INNER + ch] = av[r];
    }
}

// ---------------- K3a: CPB bias via fp16 MFMA, amortized prologue ----------------
// (unchanged from round 16)
__global__ __launch_bounds__(256) void k3a_bias(
        const float* __restrict__ pose_init, const float* __restrict__ vgrid_g,
        const float* __restrict__ w0, const float* __restrict__ b0,
        const float* __restrict__ b1, const float* __restrict__ w1,
        const float* __restrict__ w2, const float* __restrict__ b2,
        ushort_t* __restrict__ bias) {
    int bg = blockIdx.x >> 5;
    int jt = (blockIdx.x >> 1) & 15;
    int itc = blockIdx.x & 1;
    int b = bg >> 3;
    int tid = threadIdx.x;
    int wv = tid >> 6, lane = tid & 63;
    int lgp = lane >> 4, lr = lane & 15;

    __shared__ float gx_s[128], gy_s[128];
    __shared__ float2 b1w2_s[64];
    __shared__ float2 vg_s[16];
    __shared__ unsigned b0_lds[4][8];
    if (tid < 128) {
        gx_s[tid] = 2.f * pose_init[(b * 2 + 0) * NQ + itc * 128 + tid] - 1.f;
    } else {
        gy_s[tid - 128] = 2.f * pose_init[(b * 2 + 1) * NQ + itc * 128 + (tid - 128)] - 1.f;
    }
    if (tid < 64) {
        float2 bw; bw.x = b1[tid]; bw.y = w2[tid];
        b1w2_s[tid] = bw;
    } else if (tid < 80) {
        int j = jt * 16 + (tid - 64);
        vg_s[tid - 64] = ((const float2*)vgrid_g)[bg * NQ + j];
    } else if (tid < 112) {
        int idx = tid - 80;
        int lg2 = idx >> 3, rem = idx & 7, kc = rem >> 2, e2 = rem & 3;
        int c = kc * 32 + lg2 * 8 + 2 * e2;
        b0_lds[lg2][kc * 4 + e2] = pkrtz(b0[c], b0[c + 1]);
    }
    __syncthreads();

    unsigned w0a_pk[2][4], w0b_pk[2][4];
    #pragma unroll
    for (int kc = 0; kc < 2; ++kc)
        #pragma unroll
        for (int e2 = 0; e2 < 4; ++e2) {
            int c = kc * 32 + lgp * 8 + 2 * e2;
            w0a_pk[kc][e2] = pkrtz(w0[2 * c],     w0[2 * (c + 1)]);
            w0b_pk[kc][e2] = pkrtz(w0[2 * c + 1], w0[2 * (c + 1) + 1]);
        }
    half8v w1f[2][4];
    #pragma unroll
    for (int nt = 0; nt < 4; ++nt) {
        int c2 = nt * 16 + lr;
        #pragma unroll
        for (int kc = 0; kc < 2; ++kc) {
            union { half8v v; unsigned u[4]; } tmp;
            #pragma unroll
            for (int e2 = 0; e2 < 4; ++e2) {
                int kk = kc * 32 + lgp * 8 + 2 * e2;
                tmp.u[e2] = pkrtz(w1[c2 * 64 + kk], w1[c2 * 64 + kk + 1]);
            }
            w1f[kc][nt] = tmp.v;
        }
    }
    float b2v = b2[0];
    ushort_t* brow_base = bias + bg * NQ * NQ;

    #pragma unroll 1
    for (int it2 = 0; it2 < 8; ++it2) {
        int it = itc * 8 + it2;
        float gxi = gx_s[it2 * 16 + lr], gyi = gy_s[it2 * 16 + lr];
        #pragma unroll 1
        for (int jp = 0; jp < 2; ++jp) {
            int jlA = wv * 4 + jp * 2;
            int jA = jt * 16 + jlA;
            float2 vgA = vg_s[jlA], vgB = vg_s[jlA + 1];
            float pxA = gxi - vgA.x, pyA = gyi - vgA.y;
            float pxB = gxi - vgB.x, pyB = gyi - vgB.y;
            float uA = copysignf(__logf(1.f + fabsf(pxA)), pxA);
            float vA = copysignf(__logf(1.f + fabsf(pyA)), pyA);
            float uB = copysignf(__logf(1.f + fabsf(pxB)), pxB);
            float vB = copysignf(__logf(1.f + fabsf(pyB)), pyB);
            unsigned uuA = pkrtz(uA, uA), vvA = pkrtz(vA, vA);
            unsigned uuB = pkrtz(uB, uB), vvB = pkrtz(vB, vB);
            union { half8v v; unsigned u[4]; } hA0, hA1, hB0, hB1;
            #pragma unroll
            for (int e2 = 0; e2 < 4; ++e2) {
                hA0.u[e2] = pk_max0_f16(pk_fma_f16(w0a_pk[0][e2], uuA,
                              pk_fma_f16(w0b_pk[0][e2], vvA, b0_lds[lgp][e2])));
                hB0.u[e2] = pk_max0_f16(pk_fma_f16(w0a_pk[0][e2], uuB,
                              pk_fma_f16(w0b_pk[0][e2], vvB, b0_lds[lgp][e2])));
                hA1.u[e2] = pk_max0_f16(pk_fma_f16(w0a_pk[1][e2], uuA,
                              pk_fma_f16(w0b_pk[1][e2], vvA, b0_lds[lgp][4 + e2])));
                hB1.u[e2] = pk_max0_f16(pk_fma_f16(w0a_pk[1][e2], uuB,
                              pk_fma_f16(w0b_pk[1][e2], vvB, b0_lds[lgp][4 + e2])));
            }
            float sA = 0.f, sB = 0.f;
            #pragma unroll
            for (int ntp = 0; ntp < 2; ++ntp) {
                int n0t = 2 * ntp, n1t = 2 * ntp + 1;
                f32x4 aA0 = {0.f, 0.f, 0.f, 0.f};
                f32x4 aA1 = {0.f, 0.f, 0.f, 0.f};
                f32x4 aB0 = {0.f, 0.f, 0.f, 0.f};
                f32x4 aB1 = {0.f, 0.f, 0.f, 0.f};
                aA0 = __builtin_amdgcn_mfma_f32_16x16x32_f16(w1f[0][n0t], hA0.v, aA0, 0, 0, 0);
                aB0 = __builtin_amdgcn_mfma_f32_16x16x32_f16(w1f[0][n0t], hB0.v, aB0, 0, 0, 0);
                aA0 = __builtin_amdgcn_mfma_f32_16x16x32_f16(w1f[1][n0t], hA1.v, aA0, 0, 0, 0);
                aB0 = __builtin_amdgcn_mfma_f32_16x16x32_f16(w1f[1][n0t], hB1.v, aB0, 0, 0, 0);
                aA1 = __builtin_amdgcn_mfma_f32_16x16x32_f16(w1f[0][n1t], hA0.v, aA1, 0, 0, 0);
                aB1 = __builtin_amdgcn_mfma_f32_16x16x32_f16(w1f[0][n1t], hB0.v, aB1, 0, 0, 0);
                aA1 = __builtin_amdgcn_mfma_f32_16x16x32_f16(w1f[1][n1t], hA1.v, aA1, 0, 0, 0);
                aB1 = __builtin_amdgcn_mfma_f32_16x16x32_f16(w1f[1][n1t], hB1.v, aB1, 0, 0, 0);
                #pragma unroll
                for (int r = 0; r < 4; ++r) {
                    float2 bw0 = b1w2_s[n0t * 16 + 4 * lgp + r];
                    float2 bw1 = b1w2_s[n1t * 16 + 4 * lgp + r];
                    sA += fmaxf(aA0[r] + bw0.x, 0.f) * bw0.y;
                    sB += fmaxf(aB0[r] + bw0.x, 0.f) * bw0.y;
                    sA += fmaxf(aA1[r] + bw1.x, 0.f) * bw1.y;
                    sB += fmaxf(aB1[r] + bw1.x, 0.f) * bw1.y;
                }
            }
            sA += __shfl_xor(sA, 16, 64);
            sB += __shfl_xor(sB, 16, 64);
            sA += __shfl_xor(sA, 32, 64);
            sB += __shfl_xor(sB, 32, 64);
            if (lane < 16) {
                ushort_t* row = brow_base + (it * 16 + lr) * NQ + jA;
                row[0] = (ushort_t)f2bf(sA + b2v);
                row[1] = (ushort_t)f2bf(sB + b2v);
            }
        }
    }
}

// ---------------- K3b: sim + bias + softmax + attn@V (LDS-staged V) ----------------
__global__ __launch_bounds__(256) void k3b_attn(
        const float* __restrict__ qT, const float* __restrict__ kTt,
        const float* __restrict__ vT, const ushort_t* __restrict__ bias,
        float* __restrict__ aoT) {
    int bg = blockIdx.x >> 5;
    int itile = blockIdx.x & 31;
    int b = bg >> 3, h = bg & 7;
    int i0 = itile * 8;
    int tid = threadIdx.x;

    __shared__ __align__(16) float q_s[8][64];
    __shared__ __align__(16) float attn_s[8][NQ];
    __shared__ __align__(16) float vstage[64][64];
    __shared__ float ssum_s[8];

    for (int idx = tid; idx < 8 * 64; idx += 256) {
        int i = idx >> 6, d = idx & 63;
        q_s[i][d] = qT[(b * NQ + i0 + i) * INNER + h * 64 + d] * 0.125f;
    }
    __syncthreads();

    {
        int jq = tid & 63, ih = tid >> 6;
        const float4* kb4 = (const float4*)(kTt + bg * DH * NQ) + jq;
        float4 s0 = {0.f, 0.f, 0.f, 0.f};
        float4 s1 = {0.f, 0.f, 0.f, 0.f};
        #pragma unroll 8
        for (int d = 0; d < 64; ++d) {
            float4 kv = kb4[d * 64];
            float q0 = q_s[ih][d], q1 = q_s[ih + 4][d];
            s0.x = fmaf(q0, kv.x, s0.x); s0.y = fmaf(q0, kv.y, s0.y);
            s0.z = fmaf(q0, kv.z, s0.z); s0.w = fmaf(q0, kv.w, s0.w);
            s1.x = fmaf(q1, kv.x, s1.x); s1.y = fmaf(q1, kv.y, s1.y);
            s1.z = fmaf(q1, kv.z, s1.z); s1.w = fmaf(q1, kv.w, s1.w);
        }
        uint2 bb0 = *(const uint2*)(bias + (bg * NQ + i0 + ih) * NQ + jq * 4);
        uint2 bb1 = *(const uint2*)(bias + (bg * NQ + i0 + ih + 4) * NQ + jq * 4);
        s0.x += bf2f(bb0.x & 0xffffu); s0.y += bf2f(bb0.x >> 16);
        s0.z += bf2f(bb0.y & 0xffffu); s0.w += bf2f(bb0.y >> 16);
        s1.x += bf2f(bb1.x & 0xffffu); s1.y += bf2f(bb1.x >> 16);
        s1.z += bf2f(bb1.y & 0xffffu); s1.w += bf2f(bb1.y >> 16);
        *(float4*)&attn_s[ih][jq * 4] = s0;
        *(float4*)&attn_s[ih + 4][jq * 4] = s1;
    }
    __syncthreads();
    {
        int il = tid >> 5, lane = tid & 31;
        float m = -1e30f;
        for (int jj = 0; jj < 8; ++jj) m = fmaxf(m, attn_s[il][jj * 32 + lane]);
        #pragma unroll
        for (int o = 16; o > 0; o >>= 1) m = fmaxf(m, __shfl_xor(m, o, 32));
        float s = 0.f;
        for (int jj = 0; jj < 8; ++jj) {
            int j = jj * 32 + lane;
            float e = __expf(attn_s[il][j] - m);
            attn_s[il][j] = e;
            s += e;
        }
        #pragma unroll
        for (int o = 16; o > 0; o >>= 1) s += __shfl_xor(s, o, 32);
        if (lane == 0) ssum_s[il] = s;
    }
    // ---- PV over 4 LDS-staged chunks of 64 j ----
    {
        int lane = tid & 31, il = tid >> 5;
        float a0 = 0.f, a1 = 0.f, c0 = 0.f, c1 = 0.f;
        #pragma unroll 1
        for (int jc = 0; jc < 4; ++jc) {
            __syncthreads();   // previous chunk consumed / attn_s ready
            #pragma unroll
            for (int rep = 0; rep < 4; ++rep) {
                int idx = rep * 256 + tid;
                int row = idx >> 4, c4 = idx & 15;
                float4 v = *(const float4*)(vT + (b * NQ + jc * 64 + row) * INNER + h * 64 + c4 * 4);
                *(float4*)&vstage[row][c4 * 4] = v;
            }
            __syncthreads();
            const float* ar = &attn_s[il][jc * 64];
            #pragma unroll 8
            for (int j = 0; j < 64; j += 2) {
                float w0 = ar[j], w1 = ar[j + 1];
                float2 v0 = *(const float2*)&vstage[j][lane * 2];
                float2 v1 = *(const float2*)&vstage[j + 1][lane * 2];
                a0 = fmaf(w0, v0.x, a0); a1 = fmaf(w0, v0.y, a1);
                c0 = fmaf(w1, v1.x, c0); c1 = fmaf(w1, v1.y, c1);
            }
        }
        float r = 1.f / ssum_s[il];
        float2 res; res.x = (a0 + c0) * r; res.y = (a1 + c1) * r;
        *(float2*)(aoT + (b * NQ + i0 + il) * INNER + h * 64 + lane * 2) = res;
    }
}

// ---------------- K4: final projection 512 -> 256 (coalesced owT) ----------------
__global__ __launch_bounds__(256) void k4_proj(const float* __restrict__ aoT,
        const float* __restrict__ owT, const float* __restrict__ out_b,
        float* __restrict__ out) {
    int b = blockIdx.x >> 6;
    int n0 = (blockIdx.x & 63) * 4;
    int t = threadIdx.x;
    __shared__ __align__(16) float xl[4][INNER];
    for (int idx = t; idx < 4 * INNER; idx += 256) {
        xl[idx >> 9][idx & 511] = aoT[(b * NQ + n0) * INNER + idx];
    }
    __syncthreads();
    float bo = out_b[t];
    float a0 = bo, a1 = bo, a2 = bo, a3 = bo;
    #pragma unroll 2
    for (int c4 = 0; c4 < 128; ++c4) {
        int c = c4 * 4;
        float w0 = owT[(c + 0) * DIMC + t];
        float w1 = owT[(c + 1) * DIMC + t];
        float w2 = owT[(c + 2) * DIMC + t];
        float w3 = owT[(c + 3) * DIMC + t];
        float4 x0 = *(const float4*)&xl[0][c];
        float4 x1 = *(const float4*)&xl[1][c];
        float4 x2 = *(const float4*)&xl[2][c];
        float4 x3 = *(const float4*)&xl[3][c];
        a0 = fmaf(w0, x0.x, a0); a0 = fmaf(w1, x0.y, a0); a0 = fmaf(w2, x0.z, a0); a0 = fmaf(w3, x0.w, a0);
        a1 = fmaf(w0, x1.x, a1); a1 = fmaf(w1, x1.y, a1); a1 = fmaf(w2, x1.z, a1); a1 = fmaf(w3, x1.w, a1);
        a2 = fmaf(w0, x2.x, a2); a2 = fmaf(w1, x2.y, a2); a2 = fmaf(w2, x2.z, a2); a2 = fmaf(w3, x2.w, a2);
        a3 = fmaf(w0, x3.x, a3); a3 = fmaf(w1, x3.y, a3); a3 = fmaf(w2, x3.z, a3); a3 = fmaf(w3, x3.w, a3);
    }
    float4 res; res.x = a0; res.y = a1; res.z = a2; res.w = a3;
    *(float4*)(out + (b * DIMC + t) * NQ + n0) = res;
}

extern "C" void kernel_launch(void* const* d_in, const int* in_sizes, int n_in,
                              void* d_out, int out_size, void* d_ws, size_t ws_size,
                              hipStream_t stream) {
    const float* pose_feat = (const float*)d_in[0];
    const float* rgb       = (const float*)d_in[1];
    const float* pose_init = (const float*)d_in[2];
    const float* mha_in_w  = (const float*)d_in[3];
    const float* mha_in_b  = (const float*)d_in[4];
    const float* mha_out_w = (const float*)d_in[5];
    const float* mha_out_b = (const float*)d_in[6];
    const float* pe_gauss  = (const float*)d_in[7];
    const float* off_w1    = (const float*)d_in[8];
    const float* off_b1    = (const float*)d_in[9];
    const float* off_w2    = (const float*)d_in[10];
    const float* cpb_w0    = (const float*)d_in[11];
    const float* cpb_b0    = (const float*)d_in[12];
    const float* cpb_w1    = (const float*)d_in[13];
    const float* cpb_b1    = (const float*)d_in[14];
    const float* cpb_w2    = (const float*)d_in[15];
    const float* cpb_b2    = (const float*)d_in[16];
    const float* q_w       = (const float*)d_in[17];
    const float* k_w       = (const float*)d_in[18];
    const float* v_w       = (const float*)d_in[19];
    const float* out_w     = (const float*)d_in[20];
    const float* out_b     = (const float*)d_in[21];

    float* ws    = (float*)d_ws;
    float* kx    = ws;                     // 16384
    float* vx    = kx + 16384;             // 16384
    float* qT    = vx + 16384;             // 524288
    float* kTt   = qT + 524288;            // 524288
    float* vT    = kTt + 524288;           // 524288
    float* vgrid = vT + 524288;            // 16384
    float* aoT   = vgrid + 16384;          // 524288
    float* WqT   = aoT + 524288;           // 65536
    float* mowT  = WqT + 65536;            // 65536
    float* owT   = mowT + 65536;           // 131072
    float* qwT   = owT + 131072;           // 16384
    float* kwT   = qwT + 16384;            // 16384
    float* vwT   = kwT + 16384;            // 16384
    ushort_t* bias = (ushort_t*)(vwT + 16384);   // 32*256*256 bf16 = 4 MB
    float* out   = (float*)d_out;

    k0_tr<<<1216, 256, 0, stream>>>(mha_in_w, mha_out_w, out_w, q_w, k_w, v_w,
        WqT, mowT, owT, qwT, kwT, vwT);
    k1_kv<<<64, 256, 0, stream>>>(rgb, mha_in_w, mha_in_b, kx, vx);
    k2_qkv<<<256, 256, 0, stream>>>(pose_feat, rgb, pose_init, mha_in_b,
        WqT, mowT, mha_out_b, pe_gauss, off_w1, off_b1, off_w2, qwT, kwT, vwT,
        kx, vx, qT, kTt, vT, vgrid);
    k3a_bias<<<1024, 256, 0, stream>>>(pose_init, vgrid,
        cpb_w0, cpb_b0, cpb_b1, cpb_w1, cpb_w2, cpb_b2, bias);
    k3b_attn<<<1024, 256, 0, stream>>>(qT, kTt, vT, bias, aoT);
    k4_proj<<<256, 256, 0, stream>>>(aoT, owT, out_b, out);
}

// Round 18
// 146.875 us; speedup vs baseline: 1.9207x; 1.0090x over previous
//
#include <hip/hip_runtime.h>
#include <hip/hip_bf16.h>
#include <math.h>

// DeformableAttention2D — round 18: k2 occupancy fix. k2 ran at grid 256 =
// 1 block/CU = 4 waves/CU (12.5%) with barrier-separated latency-bound
// matvec phases. Now 2 rows/block, grid 512 (2 blocks/CU, 8 waves/CU).
// k3a/k3b unchanged from r17.
// Sizes (fixed): B=4, N=256, DIM=256, HEADS=8, GROUPS=8, INNER=512, DH=64,
// cross-attn head dim 32, rgb 4x4 (16 tokens), CPB MLP 2->64->64->1.

#define DIMC 256
#define NQ 256
#define HEADS 8
#define GROUPS 8
#define INNER 512
#define DH 64
#define HDX 32
#define HWT 16

typedef __attribute__((ext_vector_type(8))) short short8v;
typedef __attribute__((ext_vector_type(8))) _Float16 half8v;
typedef __attribute__((ext_vector_type(4))) float f32x4;
typedef unsigned short ushort_t;

__device__ __forceinline__ float gelu_exact(float x) {
    return 0.5f * x * (1.f + erff(x * 0.70710678118654752f));
}
__device__ __forceinline__ short f2bf(float x) {
    union { float f; unsigned u; } c; c.f = x;
    unsigned r = c.u + 0x7fffu + ((c.u >> 16) & 1u);
    return (short)(r >> 16);
}
__device__ __forceinline__ float bf2f(unsigned hbits) {
    union { unsigned u; float f; } c; c.u = hbits << 16;
    return c.f;
}
__device__ __forceinline__ unsigned pkrtz(float a, float b) {
    auto h = __builtin_amdgcn_cvt_pkrtz(a, b);
    union { decltype(h) h2; unsigned u; } c; c.h2 = h; return c.u;
}
__device__ __forceinline__ unsigned pk_fma_f16(unsigned a, unsigned b, unsigned c) {
    unsigned d;
    asm("v_pk_fma_f16 %0, %1, %2, %3" : "=v"(d) : "v"(a), "v"(b), "v"(c));
    return d;
}
__device__ __forceinline__ unsigned pk_max0_f16(unsigned a) {
    unsigned d;
    asm("v_pk_max_f16 %0, %1, %2" : "=v"(d) : "v"(a), "v"(0u));
    return d;
}
__device__ __forceinline__ float samp4(const float* __restrict__ img, int yi, int xi) {
    bool valid = (xi >= 0) && (xi < 4) && (yi >= 0) && (yi < 4);
    int idx = min(max(yi, 0), 3) * 4 + min(max(xi, 0), 3);
    return valid ? img[idx] : 0.f;
}

// ---------------- K0: weight transposes ----------------
__global__ __launch_bounds__(256) void k0_tr(
        const float* __restrict__ in_w, const float* __restrict__ mow,
        const float* __restrict__ out_w, const float* __restrict__ q_w,
        const float* __restrict__ k_w, const float* __restrict__ v_w,
        float* __restrict__ WqT, float* __restrict__ mowT,
        float* __restrict__ owT, float* __restrict__ qwT,
        float* __restrict__ kwT, float* __restrict__ vwT) {
    int idx = blockIdx.x * 256 + threadIdx.x;
    if (idx < 65536) {
        int d = idx >> 8, o = idx & 255;
        WqT[idx] = in_w[o * 256 + d];
    } else if (idx < 131072) {
        int k = idx - 65536; int d = k >> 8, o = k & 255;
        mowT[k] = mow[o * 256 + d];
    } else if (idx < 262144) {
        int k = idx - 131072; int c = k >> 8, o = k & 255;
        owT[k] = out_w[o * 512 + c];
    } else if (idx < 278528) {
        int k = idx - 262144; int ci = k >> 9, ch = k & 511;
        qwT[k] = q_w[ch * 32 + ci];
    } else if (idx < 294912) {
        int k = idx - 278528; int ci = k >> 9, ch = k & 511;
        kwT[k] = k_w[ch * 32 + ci];
    } else if (idx < 311296) {
        int k = idx - 294912; int ci = k >> 9, ch = k & 511;
        vwT[k] = v_w[ch * 32 + ci];
    }
}

// ---------------- K1: kx, vx  [b,16,256] ----------------
__global__ __launch_bounds__(256) void k1_kv(const float* __restrict__ rgb,
        const float* __restrict__ in_w, const float* __restrict__ in_b,
        float* __restrict__ kx, float* __restrict__ vx) {
    int b = blockIdx.x >> 4;
    int tt = blockIdx.x & 15;
    int c = threadIdx.x;
    __shared__ __align__(16) float kvin[DIMC];
    float ang = (float)tt * powf(10000.f, -(float)(c >> 1) * (1.f / 128.f));
    float sv = (c & 1) ? cosf(ang) : sinf(ang);
    kvin[c] = rgb[(b * DIMC + c) * HWT + tt] + sv;
    __syncthreads();
    const float4* x4 = (const float4*)kvin;
    const float4* wk4 = (const float4*)(in_w + (DIMC + c) * DIMC);
    const float4* wv4 = (const float4*)(in_w + (2 * DIMC + c) * DIMC);
    float ak0 = in_b[DIMC + c], ak1 = 0.f, av0 = in_b[2 * DIMC + c], av1 = 0.f;
    #pragma unroll 4
    for (int d4 = 0; d4 < 64; ++d4) {
        float4 x = x4[d4], wk = wk4[d4], wv = wv4[d4];
        ak0 = fmaf(wk.x, x.x, ak0); ak1 = fmaf(wk.y, x.y, ak1);
        ak0 = fmaf(wk.z, x.z, ak0); ak1 = fmaf(wk.w, x.w, ak1);
        av0 = fmaf(wv.x, x.x, av0); av1 = fmaf(wv.y, x.y, av1);
        av0 = fmaf(wv.z, x.z, av0); av1 = fmaf(wv.w, x.w, av1);
    }
    kx[(b * HWT + tt) * DIMC + c] = ak0 + ak1;
    vx[(b * HWT + tt) * DIMC + c] = av0 + av1;
}

// ---------------- K2: 2 rows per block (grid 512) ----------------
__global__ __launch_bounds__(256) void k2_qkv(
        const float* __restrict__ pose_feat, const float* __restrict__ rgb,
        const float* __restrict__ pose_init, const float* __restrict__ in_b,
        const float* __restrict__ WqT, const float* __restrict__ mowT,
        const float* __restrict__ mob, const float* __restrict__ pe_gauss,
        const float* __restrict__ off_w1, const float* __restrict__ off_b1,
        const float* __restrict__ off_w2,
        const float* __restrict__ qwT, const float* __restrict__ kwT,
        const float* __restrict__ vwT,
        const float* __restrict__ kx, const float* __restrict__ vx,
        float* __restrict__ qT, float* __restrict__ kTt, float* __restrict__ vT,
        float* __restrict__ vgrid_g) {
    int b = blockIdx.x >> 7;
    int n0 = (blockIdx.x & 127) * 2;
    int t = threadIdx.x;
    __shared__ __align__(16) float xs[2][DIMC];
    __shared__ __align__(16) float qxs[2][DIMC];
    __shared__ __align__(16) float ctx[2][DIMC];
    __shared__ __align__(16) float x2[2][DIMC];
    __shared__ float lg[2][128], psm[2][128];
    __shared__ float qls[2][INNER];
    __shared__ float kvs[2][DIMC];
    __shared__ float vg[2][GROUPS][2];
    __shared__ float g01[2][2];

    if (t < 4) {
        int r = t >> 1, comp = t & 1;
        g01[r][comp] = 2.f * pose_init[(b * 2 + comp) * NQ + n0 + r] - 1.f;
    }
    float2 pf2 = *(const float2*)(pose_feat + (b * DIMC + t) * NQ + n0);
    float pfv[2] = {pf2.x, pf2.y};
    __syncthreads();
    // point embedding
    {
        int j = t & 127;
        float pj0 = pe_gauss[j], pj1 = pe_gauss[128 + j];
        #pragma unroll
        for (int r = 0; r < 2; ++r) {
            float cc = (g01[r][0] * pj0 + g01[r][1] * pj1) * 6.28318530717958648f;
            float sc = (t < 128) ? sinf(cc) : cosf(cc);
            xs[r][t] = pfv[r] + sc;
        }
    }
    __syncthreads();
    // qx matvec (coalesced WqT)
    {
        float bq = in_b[t];
        float a0 = bq, a1 = bq;
        #pragma unroll 2
        for (int d4 = 0; d4 < 64; ++d4) {
            int d = d4 * 4;
            float w0 = WqT[(d + 0) * DIMC + t];
            float w1 = WqT[(d + 1) * DIMC + t];
            float w2 = WqT[(d + 2) * DIMC + t];
            float w3 = WqT[(d + 3) * DIMC + t];
            float4 x0 = *(const float4*)&xs[0][d];
            float4 x1 = *(const float4*)&xs[1][d];
            a0 = fmaf(w0, x0.x, a0); a0 = fmaf(w1, x0.y, a0); a0 = fmaf(w2, x0.z, a0); a0 = fmaf(w3, x0.w, a0);
            a1 = fmaf(w0, x1.x, a1); a1 = fmaf(w1, x1.y, a1); a1 = fmaf(w2, x1.z, a1); a1 = fmaf(w3, x1.w, a1);
        }
        qxs[0][t] = a0; qxs[1][t] = a1;
    }
    __syncthreads();
    // cross-attn logits: 2r x 8h x 16tt = 256 (single pass)
    {
        int r = t >> 7, hh = (t >> 4) & 7, tt = t & 15;
        const float4* kp = (const float4*)(kx + (b * HWT + tt) * DIMC + hh * HDX);
        const float4* qp = (const float4*)(&qxs[r][hh * HDX]);
        float a = 0.f;
        #pragma unroll
        for (int d4 = 0; d4 < 8; ++d4) {
            float4 k4 = kp[d4], q4 = qp[d4];
            a = fmaf(q4.x, k4.x, a); a = fmaf(q4.y, k4.y, a);
            a = fmaf(q4.z, k4.z, a); a = fmaf(q4.w, k4.w, a);
        }
        lg[r][hh * 16 + tt] = a * 0.17677669529663689f;
    }
    __syncthreads();
    if (t < 16) {
        int r = t >> 3, hh = t & 7;
        float m = -1e30f;
        for (int tt = 0; tt < 16; ++tt) m = fmaxf(m, lg[r][hh * 16 + tt]);
        float s = 0.f;
        for (int tt = 0; tt < 16; ++tt) {
            float e = __expf(lg[r][hh * 16 + tt] - m);
            psm[r][hh * 16 + tt] = e; s += e;
        }
        float rr = 1.f / s;
        for (int tt = 0; tt < 16; ++tt) psm[r][hh * 16 + tt] *= rr;
    }
    __syncthreads();
    // ctx
    {
        int hh = t >> 5;
        const float* vp = vx + b * HWT * DIMC + t;
        float a0 = 0.f, a1 = 0.f;
        #pragma unroll
        for (int tt = 0; tt < 16; ++tt) {
            float vv = vp[tt * DIMC];
            a0 = fmaf(psm[0][hh * 16 + tt], vv, a0);
            a1 = fmaf(psm[1][hh * 16 + tt], vv, a1);
        }
        ctx[0][t] = a0; ctx[1][t] = a1;
    }
    __syncthreads();
    // pose_cross matvec + residual
    {
        float bm = mob[t];
        float a0 = bm, a1 = bm;
        #pragma unroll 2
        for (int d4 = 0; d4 < 64; ++d4) {
            int d = d4 * 4;
            float w0 = mowT[(d + 0) * DIMC + t];
            float w1 = mowT[(d + 1) * DIMC + t];
            float w2 = mowT[(d + 2) * DIMC + t];
            float w3 = mowT[(d + 3) * DIMC + t];
            float4 c0 = *(const float4*)&ctx[0][d];
            float4 c1 = *(const float4*)&ctx[1][d];
            a0 = fmaf(w0, c0.x, a0); a0 = fmaf(w1, c0.y, a0); a0 = fmaf(w2, c0.z, a0); a0 = fmaf(w3, c0.w, a0);
            a1 = fmaf(w0, c1.x, a1); a1 = fmaf(w1, c1.y, a1); a1 = fmaf(w2, c1.z, a1); a1 = fmaf(w3, c1.w, a1);
        }
        x2[0][t] = pfv[0] + a0; x2[1][t] = pfv[1] + a1;
    }
    __syncthreads();
    // grouped q conv
    #pragma unroll
    for (int rep = 0; rep < 2; ++rep) {
        int ch = rep * 256 + t;
        int g = ch >> 6;
        float aq0 = 0.f, aq1 = 0.f;
        #pragma unroll
        for (int ci = 0; ci < 32; ++ci) {
            float w = qwT[ci * INNER + ch];
            aq0 = fmaf(w, x2[0][g * 32 + ci], aq0);
            aq1 = fmaf(w, x2[1][g * 32 + ci], aq1);
        }
        qls[0][ch] = aq0; qls[1][ch] = aq1;
        qT[(b * NQ + n0 + 0) * INNER + ch] = aq0;
        qT[(b * NQ + n0 + 1) * INNER + ch] = aq1;
    }
    __syncthreads();
    // offsets: 16 (r,g) pairs x 16 lanes (4 channels each)
    {
        int pr = t >> 4, l = t & 15;
        int r = pr >> 3, g = pr & 7;
        float s0 = 0.f, s1 = 0.f;
        #pragma unroll
        for (int e = 0; e < 4; ++e) {
            int jj = l * 4 + e;
            float ev = gelu_exact(fmaf(qls[r][g * 64 + jj], off_w1[jj], off_b1[jj]));
            s0 = fmaf(ev, off_w2[jj], s0);
            s1 = fmaf(ev, off_w2[64 + jj], s1);
        }
        #pragma unroll
        for (int o = 8; o > 0; o >>= 1) {
            s0 += __shfl_xor(s0, o, 64);
            s1 += __shfl_xor(s1, o, 64);
        }
        if (l == 0) {
            float vgx = g01[r][0] + tanhf(s0) * (2.f / 3.f);
            float vgy = g01[r][1] + tanhf(s1) * (2.f / 3.f);
            vg[r][g][0] = vgx; vg[r][g][1] = vgy;
            float* vp = vgrid_g + ((b * GROUPS + g) * NQ + n0 + r) * 2;
            vp[0] = vgx; vp[1] = vgy;
        }
    }
    __syncthreads();
    // bilinear grid sample: 2r x 256c
    #pragma unroll
    for (int rep = 0; rep < 2; ++rep) {
        int idx = rep * 256 + t;
        int r = idx >> 8, c = idx & 255, g = c >> 5;
        float x = (vg[r][g][0] + 1.f) * 2.f - 0.5f;
        float y = (vg[r][g][1] + 1.f) * 2.f - 0.5f;
        float x0f = floorf(x), y0f = floorf(y);
        float wx = x - x0f, wy = y - y0f;
        int x0 = (int)x0f, y0 = (int)y0f;
        const float* img = rgb + (b * DIMC + c) * HWT;
        float v00 = samp4(img, y0, x0), v01 = samp4(img, y0, x0 + 1);
        float v10 = samp4(img, y0 + 1, x0), v11 = samp4(img, y0 + 1, x0 + 1);
        kvs[r][c] = v00 * (1.f - wx) * (1.f - wy) + v01 * wx * (1.f - wy)
                  + v10 * (1.f - wx) * wy + v11 * wx * wy;
    }
    __syncthreads();
    // grouped k/v convs; K transposed [bg][d][n], V row-major [b][n][inner]
    #pragma unroll
    for (int rep = 0; rep < 2; ++rep) {
        int ch = rep * 256 + t;
        int g = ch >> 6;
        float ak0 = 0.f, ak1 = 0.f, av0 = 0.f, av1 = 0.f;
        #pragma unroll
        for (int ci = 0; ci < 32; ++ci) {
            float wk = kwT[ci * INNER + ch];
            float wv = vwT[ci * INNER + ch];
            float x0 = kvs[0][g * 32 + ci];
            float x1 = kvs[1][g * 32 + ci];
            ak0 = fmaf(wk, x0, ak0); ak1 = fmaf(wk, x1, ak1);
            av0 = fmaf(wv, x0, av0); av1 = fmaf(wv, x1, av1);
        }
        int hh = ch >> 6, dh = ch & 63;
        float2 kk; kk.x = ak0; kk.y = ak1;
        *(float2*)(kTt + ((b * HEADS + hh) * DH + dh) * NQ + n0) = kk;
        vT[(b * NQ + n0 + 0) * INNER + ch] = av0;
        vT[(b * NQ + n0 + 1) * INNER + ch] = av1;
    }
}

// ---------------- K3a: CPB bias via fp16 MFMA, amortized prologue ----------------
// (unchanged from round 16)
__global__ __launch_bounds__(256) void k3a_bias(
        const float* __restrict__ pose_init, const float* __restrict__ vgrid_g,
        const float* __restrict__ w0, const float* __restrict__ b0,
        const float* __restrict__ b1, const float* __restrict__ w1,
        const float* __restrict__ w2, const float* __restrict__ b2,
        ushort_t* __restrict__ bias) {
    int bg = blockIdx.x >> 5;
    int jt = (blockIdx.x >> 1) & 15;
    int itc = blockIdx.x & 1;
    int b = bg >> 3;
    int tid = threadIdx.x;
    int wv = tid >> 6, lane = tid & 63;
    int lgp = lane >> 4, lr = lane & 15;

    __shared__ float gx_s[128], gy_s[128];
    __shared__ float2 b1w2_s[64];
    __shared__ float2 vg_s[16];
    __shared__ unsigned b0_lds[4][8];
    if (tid < 128) {
        gx_s[tid] = 2.f * pose_init[(b * 2 + 0) * NQ + itc * 128 + tid] - 1.f;
    } else {
        gy_s[tid - 128] = 2.f * pose_init[(b * 2 + 1) * NQ + itc * 128 + (tid - 128)] - 1.f;
    }
    if (tid < 64) {
        float2 bw; bw.x = b1[tid]; bw.y = w2[tid];
        b1w2_s[tid] = bw;
    } else if (tid < 80) {
        int j = jt * 16 + (tid - 64);
        vg_s[tid - 64] = ((const float2*)vgrid_g)[bg * NQ + j];
    } else if (tid < 112) {
        int idx = tid - 80;
        int lg2 = idx >> 3, rem = idx & 7, kc = rem >> 2, e2 = rem & 3;
        int c = kc * 32 + lg2 * 8 + 2 * e2;
        b0_lds[lg2][kc * 4 + e2] = pkrtz(b0[c], b0[c + 1]);
    }
    __syncthreads();

    unsigned w0a_pk[2][4], w0b_pk[2][4];
    #pragma unroll
    for (int kc = 0; kc < 2; ++kc)
        #pragma unroll
        for (int e2 = 0; e2 < 4; ++e2) {
            int c = kc * 32 + lgp * 8 + 2 * e2;
            w0a_pk[kc][e2] = pkrtz(w0[2 * c],     w0[2 * (c + 1)]);
            w0b_pk[kc][e2] = pkrtz(w0[2 * c + 1], w0[2 * (c + 1) + 1]);
        }
    half8v w1f[2][4];
    #pragma unroll
    for (int nt = 0; nt < 4; ++nt) {
        int c2 = nt * 16 + lr;
        #pragma unroll
        for (int kc = 0; kc < 2; ++kc) {
            union { half8v v; unsigned u[4]; } tmp;
            #pragma unroll
            for (int e2 = 0; e2 < 4; ++e2) {
                int kk = kc * 32 + lgp * 8 + 2 * e2;
                tmp.u[e2] = pkrtz(w1[c2 * 64 + kk], w1[c2 * 64 + kk + 1]);
            }
            w1f[kc][nt] = tmp.v;
        }
    }
    float b2v = b2[0];
    ushort_t* brow_base = bias + bg * NQ * NQ;

    #pragma unroll 1
    for (int it2 = 0; it2 < 8; ++it2) {
        int it = itc * 8 + it2;
        float gxi = gx_s[it2 * 16 + lr], gyi = gy_s[it2 * 16 + lr];
        #pragma unroll 1
        for (int jp = 0; jp < 2; ++jp) {
            int jlA = wv * 4 + jp * 2;
            int jA = jt * 16 + jlA;
            float2 vgA = vg_s[jlA], vgB = vg_s[jlA + 1];
            float pxA = gxi - vgA.x, pyA = gyi - vgA.y;
            float pxB = gxi - vgB.x, pyB = gyi - vgB.y;
            float uA = copysignf(__logf(1.f + fabsf(pxA)), pxA);
            float vA = copysignf(__logf(1.f + fabsf(pyA)), pyA);
            float uB = copysignf(__logf(1.f + fabsf(pxB)), pxB);
            float vB = copysignf(__logf(1.f + fabsf(pyB)), pyB);
            unsigned uuA = pkrtz(uA, uA), vvA = pkrtz(vA, vA);
            unsigned uuB = pkrtz(uB, uB), vvB = pkrtz(vB, vB);
            union { half8v v; unsigned u[4]; } hA0, hA1, hB0, hB1;
            #pragma unroll
            for (int e2 = 0; e2 < 4; ++e2) {
                hA0.u[e2] = pk_max0_f16(pk_fma_f16(w0a_pk[0][e2], uuA,
                              pk_fma_f16(w0b_pk[0][e2], vvA, b0_lds[lgp][e2])));
                hB0.u[e2] = pk_max0_f16(pk_fma_f16(w0a_pk[0][e2], uuB,
                              pk_fma_f16(w0b_pk[0][e2], vvB, b0_lds[lgp][e2])));
                hA1.u[e2] = pk_max0_f16(pk_fma_f16(w0a_pk[1][e2], uuA,
                              pk_fma_f16(w0b_pk[1][e2], vvA, b0_lds[lgp][4 + e2])));
                hB1.u[e2] = pk_max0_f16(pk_fma_f16(w0a_pk[1][e2], uuB,
                              pk_fma_f16(w0b_pk[1][e2], vvB, b0_lds[lgp][4 + e2])));
            }
            float sA = 0.f, sB = 0.f;
            #pragma unroll
            for (int ntp = 0; ntp < 2; ++ntp) {
                int n0t = 2 * ntp, n1t = 2 * ntp + 1;
                f32x4 aA0 = {0.f, 0.f, 0.f, 0.f};
                f32x4 aA1 = {0.f, 0.f, 0.f, 0.f};
                f32x4 aB0 = {0.f, 0.f, 0.f, 0.f};
                f32x4 aB1 = {0.f, 0.f, 0.f, 0.f};
                aA0 = __builtin_amdgcn_mfma_f32_16x16x32_f16(w1f[0][n0t], hA0.v, aA0, 0, 0, 0);
                aB0 = __builtin_amdgcn_mfma_f32_16x16x32_f16(w1f[0][n0t], hB0.v, aB0, 0, 0, 0);
                aA0 = __builtin_amdgcn_mfma_f32_16x16x32_f16(w1f[1][n0t], hA1.v, aA0, 0, 0, 0);
                aB0 = __builtin_amdgcn_mfma_f32_16x16x32_f16(w1f[1][n0t], hB1.v, aB0, 0, 0, 0);
                aA1 = __builtin_amdgcn_mfma_f32_16x16x32_f16(w1f[0][n1t], hA0.v, aA1, 0, 0, 0);
                aB1 = __builtin_amdgcn_mfma_f32_16x16x32_f16(w1f[0][n1t], hB0.v, aB1, 0, 0, 0);
                aA1 = __builtin_amdgcn_mfma_f32_16x16x32_f16(w1f[1][n1t], hA1.v, aA1, 0, 0, 0);
                aB1 = __builtin_amdgcn_mfma_f32_16x16x32_f16(w1f[1][n1t], hB1.v, aB1, 0, 0, 0);
                #pragma unroll
                for (int r = 0; r < 4; ++r) {
                    float2 bw0 = b1w2_s[n0t * 16 + 4 * lgp + r];
                    float2 bw1 = b1w2_s[n1t * 16 + 4 * lgp + r];
                    sA += fmaxf(aA0[r] + bw0.x, 0.f) * bw0.y;
                    sB += fmaxf(aB0[r] + bw0.x, 0.f) * bw0.y;
                    sA += fmaxf(aA1[r] + bw1.x, 0.f) * bw1.y;
                    sB += fmaxf(aB1[r] + bw1.x, 0.f) * bw1.y;
                }
            }
            sA += __shfl_xor(sA, 16, 64);
            sB += __shfl_xor(sB, 16, 64);
            sA += __shfl_xor(sA, 32, 64);
            sB += __shfl_xor(sB, 32, 64);
            if (lane < 16) {
                ushort_t* row = brow_base + (it * 16 + lr) * NQ + jA;
                row[0] = (ushort_t)f2bf(sA + b2v);
                row[1] = (ushort_t)f2bf(sB + b2v);
            }
        }
    }
}

// ---------------- K3b: sim + bias + softmax + attn@V (LDS-staged V) ----------------
__global__ __launch_bounds__(256) void k3b_attn(
        const float* __restrict__ qT, const float* __restrict__ kTt,
        const float* __restrict__ vT, const ushort_t* __restrict__ bias,
        float* __restrict__ aoT) {
    int bg = blockIdx.x >> 5;
    int itile = blockIdx.x & 31;
    int b = bg >> 3, h = bg & 7;
    int i0 = itile * 8;
    int tid = threadIdx.x;

    __shared__ __align__(16) float q_s[8][64];
    __shared__ __align__(16) float attn_s[8][NQ];
    __shared__ __align__(16) float vstage[64][64];
    __shared__ float ssum_s[8];

    for (int idx = tid; idx < 8 * 64; idx += 256) {
        int i = idx >> 6, d = idx & 63;
        q_s[i][d] = qT[(b * NQ + i0 + i) * INNER + h * 64 + d] * 0.125f;
    }
    __syncthreads();

    {
        int jq = tid & 63, ih = tid >> 6;
        const float4* kb4 = (const float4*)(kTt + bg * DH * NQ) + jq;
        float4 s0 = {0.f, 0.f, 0.f, 0.f};
        float4 s1 = {0.f, 0.f, 0.f, 0.f};
        #pragma unroll 8
        for (int d = 0; d < 64; ++d) {
            float4 kv = kb4[d * 64];
            float q0 = q_s[ih][d], q1 = q_s[ih + 4][d];
            s0.x = fmaf(q0, kv.x, s0.x); s0.y = fmaf(q0, kv.y, s0.y);
            s0.z = fmaf(q0, kv.z, s0.z); s0.w = fmaf(q0, kv.w, s0.w);
            s1.x = fmaf(q1, kv.x, s1.x); s1.y = fmaf(q1, kv.y, s1.y);
            s1.z = fmaf(q1, kv.z, s1.z); s1.w = fmaf(q1, kv.w, s1.w);
        }
        uint2 bb0 = *(const uint2*)(bias + (bg * NQ + i0 + ih) * NQ + jq * 4);
        uint2 bb1 = *(const uint2*)(bias + (bg * NQ + i0 + ih + 4) * NQ + jq * 4);
        s0.x += bf2f(bb0.x & 0xffffu); s0.y += bf2f(bb0.x >> 16);
        s0.z += bf2f(bb0.y & 0xffffu); s0.w += bf2f(bb0.y >> 16);
        s1.x += bf2f(bb1.x & 0xffffu); s1.y += bf2f(bb1.x >> 16);
        s1.z += bf2f(bb1.y & 0xffffu); s1.w += bf2f(bb1.y >> 16);
        *(float4*)&attn_s[ih][jq * 4] = s0;
        *(float4*)&attn_s[ih + 4][jq * 4] = s1;
    }
    __syncthreads();
    {
        int il = tid >> 5, lane = tid & 31;
        float m = -1e30f;
        for (int jj = 0; jj < 8; ++jj) m = fmaxf(m, attn_s[il][jj * 32 + lane]);
        #pragma unroll
        for (int o = 16; o > 0; o >>= 1) m = fmaxf(m, __shfl_xor(m, o, 32));
        float s = 0.f;
        for (int jj = 0; jj < 8; ++jj) {
            int j = jj * 32 + lane;
            float e = __expf(attn_s[il][j] - m);
            attn_s[il][j] = e;
            s += e;
        }
        #pragma unroll
        for (int o = 16; o > 0; o >>= 1) s += __shfl_xor(s, o, 32);
        if (lane == 0) ssum_s[il] = s;
    }
    // ---- PV over 4 LDS-staged chunks of 64 j ----
    {
        int lane = tid & 31, il = tid >> 5;
        float a0 = 0.f, a1 = 0.f, c0 = 0.f, c1 = 0.f;
        #pragma unroll 1
        for (int jc = 0; jc < 4; ++jc) {
            __syncthreads();
            #pragma unroll
            for (int rep = 0; rep < 4; ++rep) {
                int idx = rep * 256 + tid;
                int row = idx >> 4, c4 = idx & 15;
                float4 v = *(const float4*)(vT + (b * NQ + jc * 64 + row) * INNER + h * 64 + c4 * 4);
                *(float4*)&vstage[row][c4 * 4] = v;
            }
            __syncthreads();
            const float* ar = &attn_s[il][jc * 64];
            #pragma unroll 8
            for (int j = 0; j < 64; j += 2) {
                float w0 = ar[j], w1 = ar[j + 1];
                float2 v0 = *(const float2*)&vstage[j][lane * 2];
                float2 v1 = *(const float2*)&vstage[j + 1][lane * 2];
                a0 = fmaf(w0, v0.x, a0); a1 = fmaf(w0, v0.y, a1);
                c0 = fmaf(w1, v1.x, c0); c1 = fmaf(w1, v1.y, c1);
            }
        }
        float r = 1.f / ssum_s[il];
        float2 res; res.x = (a0 + c0) * r; res.y = (a1 + c1) * r;
        *(float2*)(aoT + (b * NQ + i0 + il) * INNER + h * 64 + lane * 2) = res;
    }
}

// ---------------- K4: final projection 512 -> 256 (coalesced owT) ----------------
__global__ __launch_bounds__(256) void k4_proj(const float* __restrict__ aoT,
        const float* __restrict__ owT, const float* __restrict__ out_b,
        float* __restrict__ out) {
    int b = blockIdx.x >> 6;
    int n0 = (blockIdx.x & 63) * 4;
    int t = threadIdx.x;
    __shared__ __align__(16) float xl[4][INNER];
    for (int idx = t; idx < 4 * INNER; idx += 256) {
        xl[idx >> 9][idx & 511] = aoT[(b * NQ + n0) * INNER + idx];
    }
    __syncthreads();
    float bo = out_b[t];
    float a0 = bo, a1 = bo, a2 = bo, a3 = bo;
    #pragma unroll 2
    for (int c4 = 0; c4 < 128; ++c4) {
        int c = c4 * 4;
        float w0 = owT[(c + 0) * DIMC + t];
        float w1 = owT[(c + 1) * DIMC + t];
        float w2 = owT[(c + 2) * DIMC + t];
        float w3 = owT[(c + 3) * DIMC + t];
        float4 x0 = *(const float4*)&xl[0][c];
        float4 x1 = *(const float4*)&xl[1][c];
        float4 x2 = *(const float4*)&xl[2][c];
        float4 x3 = *(const float4*)&xl[3][c];
        a0 = fmaf(w0, x0.x, a0); a0 = fmaf(w1, x0.y, a0); a0 = fmaf(w2, x0.z, a0); a0 = fmaf(w3, x0.w, a0);
        a1 = fmaf(w0, x1.x, a1); a1 = fmaf(w1, x1.y, a1); a1 = fmaf(w2, x1.z, a1); a1 = fmaf(w3, x1.w, a1);
        a2 = fmaf(w0, x2.x, a2); a2 = fmaf(w1, x2.y, a2); a2 = fmaf(w2, x2.z, a2); a2 = fmaf(w3, x2.w, a2);
        a3 = fmaf(w0, x3.x, a3); a3 = fmaf(w1, x3.y, a3); a3 = fmaf(w2, x3.z, a3); a3 = fmaf(w3, x3.w, a3);
    }
    float4 res; res.x = a0; res.y = a1; res.z = a2; res.w = a3;
    *(float4*)(out + (b * DIMC + t) * NQ + n0) = res;
}

extern "C" void kernel_launch(void* const* d_in, const int* in_sizes, int n_in,
                              void* d_out, int out_size, void* d_ws, size_t ws_size,
                              hipStream_t stream) {
    const float* pose_feat = (const float*)d_in[0];
    const float* rgb       = (const float*)d_in[1];
    const float* pose_init = (const float*)d_in[2];
    const float* mha_in_w  = (const float*)d_in[3];
    const float* mha_in_b  = (const float*)d_in[4];
    const float* mha_out_w = (const float*)d_in[5];
    const float* mha_out_b = (const float*)d_in[6];
    const float* pe_gauss  = (const float*)d_in[7];
    const float* off_w1    = (const float*)d_in[8];
    const float* off_b1    = (const float*)d_in[9];
    const float* off_w2    = (const float*)d_in[10];
    const float* cpb_w0    = (const float*)d_in[11];
    const float* cpb_b0    = (const float*)d_in[12];
    const float* cpb_w1    = (const float*)d_in[13];
    const float* cpb_b1    = (const float*)d_in[14];
    const float* cpb_w2    = (const float*)d_in[15];
    const float* cpb_b2    = (const float*)d_in[16];
    const float* q_w       = (const float*)d_in[17];
    const float* k_w       = (const float*)d_in[18];
    const float* v_w       = (const float*)d_in[19];
    const float* out_w     = (const float*)d_in[20];
    const float* out_b     = (const float*)d_in[21];

    float* ws    = (float*)d_ws;
    float* kx    = ws;                     // 16384
    float* vx    = kx + 16384;             // 16384
    float* qT    = vx + 16384;             // 524288
    float* kTt   = qT + 524288;            // 524288
    float* vT    = kTt + 524288;           // 524288
    float* vgrid = vT + 524288;            // 16384
    float* aoT   = vgrid + 16384;          // 524288
    float* WqT   = aoT + 524288;           // 65536
    float* mowT  = WqT + 65536;            // 65536
    float* owT   = mowT + 65536;           // 131072
    float* qwT   = owT + 131072;           // 16384
    float* kwT   = qwT + 16384;            // 16384
    float* vwT   = kwT + 16384;            // 16384
    ushort_t* bias = (ushort_t*)(vwT + 16384);   // 32*256*256 bf16 = 4 MB
    float* out   = (float*)d_out;

    k0_tr<<<1216, 256, 0, stream>>>(mha_in_w, mha_out_w, out_w, q_w, k_w, v_w,
        WqT, mowT, owT, qwT, kwT, vwT);
    k1_kv<<<64, 256, 0, stream>>>(rgb, mha_in_w, mha_in_b, kx, vx);
    k2_qkv<<<512, 256, 0, stream>>>(pose_feat, rgb, pose_init, mha_in_b,
        WqT, mowT, mha_out_b, pe_gauss, off_w1, off_b1, off_w2, qwT, kwT, vwT,
        kx, vx, qT, kTt, vT, vgrid);
    k3a_bias<<<1024, 256, 0, stream>>>(pose_init, vgrid,
        cpb_w0, cpb_b0, cpb_b1, cpb_w1, cpb_w2, cpb_b2, bias);
    k3b_attn<<<1024, 256, 0, stream>>>(qT, kTt, vT, bias, aoT);
    k4_proj<<<256, 256, 0, stream>>>(aoT, owT, out_b, out);
}